// Round 12
// baseline (97.676 us; speedup 1.0000x reference)
//
#include <hip/hip_runtime.h>
#include <math.h>

// ---------------------------------------------------------------------------
// WCSA round 12 = round 11 (passing, 87.6us) + three independent cuts:
//  (1) spatial: 4-wave blocks / 64 q-rows / grid 512 -> 2 blocks/CU so one
//      block's compute hides the other's staging barriers (r11 had 1/CU).
//  (2) projection GEMMs: m97-style global_load_lds width-16 staging into
//      LINEAR [128][64] LDS (no padding - gload_lds writes base+lane*16).
//  (3) channel QK: 16 chunks (grid 256 = 1 block/CU; was 128 = 0.5/CU).
// All math paths bit-identical to verified r11 versions.
// ---------------------------------------------------------------------------

constexpr int Bb = 4, Nn = 2048, Hh = 4;
constexpr int PROJ_EL = Nn * 256;          // elements per batch, 256-col proj
constexpr int HEAD_EL = Nn * 64;           // elements per (b,h) head, d=64

typedef __attribute__((ext_vector_type(8))) short short8_t;   // 8 bf16
typedef __attribute__((ext_vector_type(4))) float f32x4;

__device__ __forceinline__ ushort f2bf(float x) {
    union { float f; unsigned u; } v; v.f = x;
    unsigned r = v.u + 0x7fffu + ((v.u >> 16) & 1u);   // RNE
    return (ushort)(r >> 16);
}
__device__ __forceinline__ float bf2f(ushort x) {
    union { unsigned u; float f; } v; v.u = ((unsigned)x) << 16;
    return v.f;
}
// async global->LDS, 16B per lane; LDS dest = wave-uniform base + lane*16
__device__ __forceinline__ void gl_lds16(const ushort* g, ushort* l) {
    __builtin_amdgcn_global_load_lds(
        (const __attribute__((address_space(1))) void*)g,
        (__attribute__((address_space(3))) void*)l, 16, 0, 0);
}

// ---------------- workspace layout (float granularity) ---------------------
constexpr size_t OFF_SB    = 0;                                   // s bf16
constexpr size_t OFF_SHB   = OFF_SB   + 1024 * 1024;              // sh bf16
constexpr size_t OFF_HB    = OFF_SHB  + 1024 * 1024;              // h bf16
constexpr size_t OFF_WQC   = OFF_HB   + 256 * 1024;               // Wq_c bf16
constexpr size_t OFF_WCAT  = OFF_WQC  + 32 * 1024;                // 4x64K el
constexpr size_t OFF_PQC   = OFF_WCAT + 128 * 1024;               // bf16 (8192,256)
constexpr size_t OFF_PQS   = OFF_PQC  + 1024 * 1024;
constexpr size_t OFF_PKC   = OFF_PQS  + 1024 * 1024;
constexpr size_t OFF_PVC   = OFF_PKC  + 1024 * 1024;
constexpr size_t OFF_PKS   = OFF_PVC  + 1024 * 1024;
constexpr size_t OFF_PVST  = OFF_PKS  + 1024 * 1024;              // bf16 (B,H,16,2048)
constexpr size_t OFF_PART  = OFF_PVST + 256 * 1024;               // f32 16*16*4096 = 1M
constexpr size_t OFF_SCA   = OFF_PART + 1024 * 1024;              // bf16 16*4096
constexpr size_t OFF_WVS   = OFF_SCA  + 32 * 1024;                // Wv_s bf16 (64,64)

constexpr int QK_CHUNKS = 16;

// ---------------------------------------------------------------------------
// Convert all needed f32 arrays to bf16 in one pass. 8 elements per thread.
// ---------------------------------------------------------------------------
constexpr unsigned SEG0 = 2097152;              // s
constexpr unsigned SEG1 = SEG0 + 2097152;       // sh
constexpr unsigned SEG2 = SEG1 + 524288;        // h
constexpr unsigned SEG3 = SEG2 + 65536;         // Wq_c
constexpr unsigned SEG4 = SEG3 + 65536;         // Wq_s  -> Wcat+0
constexpr unsigned SEG5 = SEG4 + 65536;         // Wk_c  -> Wcat+65536
constexpr unsigned SEG6 = SEG5 + 65536;         // Wv_c  -> Wcat+131072
constexpr unsigned SEG7 = SEG6 + 65536;         // Wk_s  -> Wcat+196608
constexpr unsigned SEG8 = SEG7 + 4096;          // Wv_s

__global__ __launch_bounds__(256) void convert_all(
    const float* __restrict__ s, const float* __restrict__ sh,
    const float* __restrict__ h, const float* __restrict__ wqc,
    const float* __restrict__ wqs, const float* __restrict__ wkc,
    const float* __restrict__ wvc, const float* __restrict__ wks,
    const float* __restrict__ wvs,
    ushort* __restrict__ sb, ushort* __restrict__ shb, ushort* __restrict__ hb,
    ushort* __restrict__ wqcb, ushort* __restrict__ wcatb, ushort* __restrict__ wvsb)
{
    unsigned e = (blockIdx.x * 256u + threadIdx.x) * 8u;
    if (e >= SEG8) return;
    const float* src; ushort* dst; unsigned off;
    if      (e < SEG0) { src = s;   dst = sb;             off = e; }
    else if (e < SEG1) { src = sh;  dst = shb;            off = e - SEG0; }
    else if (e < SEG2) { src = h;   dst = hb;             off = e - SEG1; }
    else if (e < SEG3) { src = wqc; dst = wqcb;           off = e - SEG2; }
    else if (e < SEG4) { src = wqs; dst = wcatb;          off = e - SEG3; }
    else if (e < SEG5) { src = wkc; dst = wcatb + 65536;  off = e - SEG4; }
    else if (e < SEG6) { src = wvc; dst = wcatb + 131072; off = e - SEG5; }
    else if (e < SEG7) { src = wks; dst = wcatb + 196608; off = e - SEG6; }
    else               { src = wvs; dst = wvsb;           off = e - SEG7; }
    float4 f0 = *(const float4*)&src[off];
    float4 f1 = *(const float4*)&src[off + 4];
    short8_t o;
    o[0] = f2bf(f0.x); o[1] = f2bf(f0.y); o[2] = f2bf(f0.z); o[3] = f2bf(f0.w);
    o[4] = f2bf(f1.x); o[5] = f2bf(f1.y); o[6] = f2bf(f1.z); o[7] = f2bf(f1.w);
    *(short8_t*)&dst[off] = o;
}

// ---------------------------------------------------------------------------
// bf16 MFMA GEMM with global_load_lds staging (m97 pattern): linear
// [128][64] LDS tiles, 4 x 1KB gload_lds per wave per matrix per K-step.
// C = X(M,K) @ W(Ntot,K)^T, bf16 out, segment-routed. 128x128 tile, BK=64.
// ---------------------------------------------------------------------------
__global__ __launch_bounds__(256) void mfma_gemm(
    const ushort* __restrict__ X, const ushort* __restrict__ W,
    ushort* __restrict__ d0, ushort* __restrict__ d1,
    ushort* __restrict__ d2, ushort* __restrict__ d3, int K)
{
    __shared__ ushort Xs[128][64];
    __shared__ ushort Ws[128][64];
    const int t = threadIdx.x;
    const int w = t >> 6, l = t & 63, c = l & 15, g = l >> 4;
    const int wr = w >> 1, wc = w & 1;
    const int m0 = blockIdx.y * 128, n0 = blockIdx.x * 128;
    const int r8 = l >> 3, cseg = (l & 7) * 8;   // gload: 8 lanes/row, 8 el/lane

    f32x4 acc[4][4] = {};

    for (int k0 = 0; k0 < K; k0 += 64) {
        // stage both tiles: wave w covers rows w*32..w*32+31 (4 x 1KB each)
        #pragma unroll
        for (int q = 0; q < 4; ++q) {
            const int row = w * 32 + q * 8;
            gl_lds16(&X[(size_t)(m0 + row + r8) * K + k0 + cseg], &Xs[row][0]);
            gl_lds16(&W[(size_t)(n0 + row + r8) * K + k0 + cseg], &Ws[row][0]);
        }
        __syncthreads();   // compiler drains vmcnt before barrier
        #pragma unroll
        for (int ks = 0; ks < 2; ++ks) {
            short8_t af[4], bf[4];
            #pragma unroll
            for (int rt = 0; rt < 4; ++rt)
                af[rt] = *(const short8_t*)&Xs[wr * 64 + rt * 16 + c][ks * 32 + 8 * g];
            #pragma unroll
            for (int ct = 0; ct < 4; ++ct)
                bf[ct] = *(const short8_t*)&Ws[wc * 64 + ct * 16 + c][ks * 32 + 8 * g];
            #pragma unroll
            for (int rt = 0; rt < 4; ++rt)
                #pragma unroll
                for (int ct = 0; ct < 4; ++ct)
                    acc[rt][ct] = __builtin_amdgcn_mfma_f32_16x16x32_bf16(
                        af[rt], bf[ct], acc[rt][ct], 0, 0, 0);
        }
        __syncthreads();   // protect LDS before next-iter staging
    }

    const int seg = n0 >> 8;
    ushort* dst = seg == 0 ? d0 : seg == 1 ? d1 : seg == 2 ? d2 : d3;
    const int colbase = (n0 & 255) + wc * 64;
    #pragma unroll
    for (int rt = 0; rt < 4; ++rt)
        #pragma unroll
        for (int ct = 0; ct < 4; ++ct)
            #pragma unroll
            for (int r = 0; r < 4; ++r) {
                int mrow = m0 + wr * 64 + rt * 16 + 4 * g + r;
                int col = colbase + ct * 16 + c;
                dst[(size_t)mrow * 256 + col] = f2bf(acc[rt][ct][r]);
            }
}

// ---------------------------------------------------------------------------
// v_s^T producer with raw-reshape-aware scatter (verified round 6).
// ---------------------------------------------------------------------------
__global__ __launch_bounds__(256) void mfma_gemm_vs(
    const ushort* __restrict__ Wvs, const ushort* __restrict__ Hb,
    ushort* __restrict__ Cvt)
{
    const int t = threadIdx.x;
    const int w = t >> 6, l = t & 63, c = l & 15, g = l >> 4;
    const int n0 = blockIdx.x * 256 + w * 64;

    f32x4 acc[4][4] = {};
    #pragma unroll
    for (int ks = 0; ks < 2; ++ks) {
        short8_t af[4], bfr[4];
        #pragma unroll
        for (int rt = 0; rt < 4; ++rt)
            af[rt] = *(const short8_t*)&Wvs[(size_t)(rt * 16 + c) * 64 + ks * 32 + 8 * g];
        #pragma unroll
        for (int ct = 0; ct < 4; ++ct)
            bfr[ct] = *(const short8_t*)&Hb[(size_t)(n0 + ct * 16 + c) * 64 + ks * 32 + 8 * g];
        #pragma unroll
        for (int rt = 0; rt < 4; ++rt)
            #pragma unroll
            for (int ct = 0; ct < 4; ++ct)
                acc[rt][ct] = __builtin_amdgcn_mfma_f32_16x16x32_bf16(
                    af[rt], bfr[ct], acc[rt][ct], 0, 0, 0);
    }
    #pragma unroll
    for (int rt = 0; rt < 4; ++rt)
        #pragma unroll
        for (int ct = 0; ct < 4; ++ct)
            #pragma unroll
            for (int r = 0; r < 4; ++r) {
                int cc = rt * 16 + 4 * g + r;       // output channel 0..63
                int m  = n0 + ct * 16 + c;          // global row 0..8191
                int b  = m >> 11, n = m & 2047;
                int L  = n * 64 + cc;               // within-batch flat index
                int hh = L >> 15;
                int k  = (L & 32767) >> 4;
                int d  = L & 15;
                Cvt[(size_t)((b * 4 + hh) * 16 + d) * 2048 + k] = f2bf(acc[rt][ct][r]);
            }
}

// ---------------------------------------------------------------------------
// Channel stage 1 (f32 compute, bf16 input). 16 chunks of 128 rows each;
// grid (16,4,4) = 256 blocks (1/CU; was 0.5/CU at 8 chunks).
// ---------------------------------------------------------------------------
__global__ __launch_bounds__(256) void chan_qk_partial(const ushort* __restrict__ Pqc,
                                                       const ushort* __restrict__ Pkc,
                                                       float* __restrict__ part)
{
    const int ch = blockIdx.x, hh = blockIdx.y, b = blockIdx.z;
    const ushort* Q = Pqc + (size_t)b * PROJ_EL + (size_t)hh * HEAD_EL;
    const ushort* Kk = Pkc + (size_t)b * PROJ_EL + (size_t)hh * HEAD_EL;
    __shared__ float Qs[64][68], Ks[64][68];
    const int t = threadIdx.x, ty = t >> 4, tx = t & 15;

    float acc[4][4] = {};
    for (int sub = 0; sub < 2; ++sub) {
        const int r0 = ch * 128 + sub * 64;
        __syncthreads();
        #pragma unroll
        for (int q = t; q < 512; q += 256) {
            int row = q >> 3, c8 = (q & 7) * 8;
            short8_t qv = *(const short8_t*)&Q[(size_t)(r0 + row) * 64 + c8];
            short8_t kv = *(const short8_t*)&Kk[(size_t)(r0 + row) * 64 + c8];
            #pragma unroll
            for (int j = 0; j < 8; ++j) {
                Qs[row][c8 + j] = bf2f((ushort)qv[j]);
                Ks[row][c8 + j] = bf2f((ushort)kv[j]);
            }
        }
        __syncthreads();
        #pragma unroll 8
        for (int nn = 0; nn < 64; ++nn) {
            float4 q4 = *(const float4*)&Qs[nn][ty * 4];
            float4 k4 = *(const float4*)&Ks[nn][tx * 4];
            float qa[4] = {q4.x, q4.y, q4.z, q4.w};
            float ka[4] = {k4.x, k4.y, k4.z, k4.w};
            #pragma unroll
            for (int ii = 0; ii < 4; ++ii)
                #pragma unroll
                for (int jj = 0; jj < 4; ++jj)
                    acc[ii][jj] += qa[ii] * ka[jj];
        }
    }
    float* P = part + (((size_t)(b * 4 + hh) * QK_CHUNKS + ch) << 12);
    #pragma unroll
    for (int ii = 0; ii < 4; ++ii)
        *(float4*)&P[(ty * 4 + ii) * 64 + tx * 4] =
            make_float4(acc[ii][0], acc[ii][1], acc[ii][2], acc[ii][3]);
}

// ---------------------------------------------------------------------------
// Channel stage 2: reduce 16 partials, scale, softmax rows -> bf16 Sca.
// ---------------------------------------------------------------------------
__global__ __launch_bounds__(64) void chan_softmax(const float* __restrict__ part,
                                                   const float* __restrict__ temp,
                                                   ushort* __restrict__ Sca)
{
    const int bh = blockIdx.x;
    const int hsel = bh & 3;
    const int i = threadIdx.x;
    __shared__ float Ss[64][65];
    const float sT = 0.125f * temp[hsel];

    float m = -1e30f;
    for (int j = 0; j < 64; ++j) {
        float v = 0.f;
        #pragma unroll
        for (int cc = 0; cc < QK_CHUNKS; ++cc)
            v += part[((size_t)bh * QK_CHUNKS + cc) * 4096 + i * 64 + j];
        v *= sT;
        Ss[i][j] = v;
        m = fmaxf(m, v);
    }
    float sum = 0.f;
    for (int j = 0; j < 64; ++j) {
        float p = __expf(Ss[i][j] - m);
        Ss[i][j] = p;
        sum += p;
    }
    const float inv = 1.0f / sum;
    for (int j = 0; j < 64; ++j)
        Sca[((size_t)bh << 12) + i * 64 + j] = f2bf(Ss[i][j] * inv);
}

// ---------------------------------------------------------------------------
// Channel stage 3 via MFMA — unchanged from round 3 (verified).
// ---------------------------------------------------------------------------
__global__ __launch_bounds__(256) void chan_pv_mfma(const ushort* __restrict__ Sca,
                                                    const ushort* __restrict__ Pvc,
                                                    float* __restrict__ out)
{
    const int nc = blockIdx.x, hh = blockIdx.y, b = blockIdx.z;
    const int t = threadIdx.x;
    const int w = t >> 6, l = t & 63, c = l & 15, g = l >> 4;

    const ushort* S = Sca + ((size_t)(b * 4 + hh) << 12);
    const ushort* V = Pvc + (size_t)b * PROJ_EL + (size_t)hh * HEAD_EL;
    const int n0w = nc * 256 + w * 64;

    f32x4 acc[4][4] = {};
    #pragma unroll
    for (int ks = 0; ks < 2; ++ks) {
        short8_t af[4], bfr[4];
        #pragma unroll
        for (int rt = 0; rt < 4; ++rt)
            af[rt] = *(const short8_t*)&S[(size_t)(rt * 16 + c) * 64 + ks * 32 + 8 * g];
        #pragma unroll
        for (int ct = 0; ct < 4; ++ct)
            bfr[ct] = *(const short8_t*)&V[(size_t)(n0w + ct * 16 + c) * 64 + ks * 32 + 8 * g];
        #pragma unroll
        for (int rt = 0; rt < 4; ++rt)
            #pragma unroll
            for (int ct = 0; ct < 4; ++ct)
                acc[rt][ct] = __builtin_amdgcn_mfma_f32_16x16x32_bf16(
                    af[rt], bfr[ct], acc[rt][ct], 0, 0, 0);
    }

    float* ob = out + (size_t)b * (Nn * 320);
    #pragma unroll
    for (int rt = 0; rt < 4; ++rt)
        #pragma unroll
        for (int ct = 0; ct < 4; ++ct)
            #pragma unroll
            for (int r = 0; r < 4; ++r) {
                int i = rt * 16 + 4 * g + r;
                int nn = n0w + ct * 16 + c;
                int rem = hh * 131072 + i * 2048 + nn;
                ob[(rem >> 8) * 320 + (rem & 255)] = acc[rt][ct][r];
            }
}

// ---------------------------------------------------------------------------
// Spatial attention, round 12. 4 waves/block, 64 q-rows/block, grid 512
// (XCD-decoded: 2 heads/XCD) -> 2 blocks/CU so barrier stalls of one block
// hide under the other's compute. Per tile: block stages K (64x64) + V^T
// (16x64) into double-buffered padded LDS (reg-staged, issued a tile early).
// Math identical to r11 (verified): swapped QK^T, lane-local softmax,
// no max-subtraction.
// ---------------------------------------------------------------------------
__global__ __launch_bounds__(256, 2) void spatial_attn8(
    const ushort* __restrict__ Pqs, const ushort* __restrict__ Pks,
    const ushort* __restrict__ PvsT, const float* __restrict__ temp2,
    float* __restrict__ out)
{
    // XCD-aware decode: 512 blocks; xcd = i&7 serves heads xcd and xcd+8
    const int i0 = blockIdx.x;
    const int xcd = i0 & 7, j = i0 >> 3;       // j in [0,64)
    const int hsel = xcd + 8 * (j & 1);        // 0..15 = b*4+hh
    const int qb = j >> 1;                     // 0..31
    const int b = hsel >> 2, hh = hsel & 3;

    const int t = threadIdx.x, w = t >> 6, l = t & 63;
    const int c = l & 15, g = l >> 4;

    __shared__ ushort Kbuf[2][64][72];         // 18.4 KB
    __shared__ ushort Vbuf[2][16][72];         //  4.6 KB
    __shared__ ushort P_lds[4][16][72];        //  9.2 KB (per-wave P tile)

    const ushort* Qh = Pqs + (size_t)b * PROJ_EL + (size_t)hh * HEAD_EL;
    const ushort* Kh = Pks + (size_t)b * PROJ_EL + (size_t)hh * HEAD_EL;
    const ushort* Vt = PvsT + (size_t)((b * 4 + hh) * 16) * 2048;   // (16, 2048)
    const float sT2 = 0.125f * temp2[hh] * 1.44269504f;   // fold log2(e)

    const int q0 = qb * 64 + w * 16;
    const ushort* qp = Qh + (size_t)(q0 + c) * 64 + 8 * g;
    const short8_t qf0 = *(const short8_t*)qp;
    const short8_t qf1 = *(const short8_t*)(qp + 32);

    f32x4 oacc = {0.f, 0.f, 0.f, 0.f};
    float lsum = 0.f;
    ushort* Pw = &P_lds[w][0][0];              // row stride 72 ushorts

    // staging geometry: K 8KB -> 256 thr x 32B; V 2KB -> 256 thr x 8B
    const int krow = t >> 2, ksub = (t & 3) * 16;
    const int vrow = t >> 4, vcol = (t & 15) * 4;

    // prologue: stage tile 0 into buffer 0
    short8_t kreg0 = *(const short8_t*)&Kh[(size_t)krow * 64 + ksub];
    short8_t kreg1 = *(const short8_t*)&Kh[(size_t)krow * 64 + ksub + 8];
    uint2 vreg = *(const uint2*)&Vt[(size_t)vrow * 2048 + vcol];
    *(short8_t*)&Kbuf[0][krow][ksub]     = kreg0;
    *(short8_t*)&Kbuf[0][krow][ksub + 8] = kreg1;
    *(uint2*)&Vbuf[0][vrow][vcol] = vreg;

    for (int kt = 0; kt < 32; ++kt) {
        const int kb = kt * 64;
        const int cur = kt & 1;

        // issue next tile's global loads now; latency hides under compute
        if (kt < 31) {
            kreg0 = *(const short8_t*)&Kh[(size_t)(kb + 64 + krow) * 64 + ksub];
            kreg1 = *(const short8_t*)&Kh[(size_t)(kb + 64 + krow) * 64 + ksub + 8];
            vreg = *(const uint2*)&Vt[(size_t)vrow * 2048 + kb + 64 + vcol];
        }

        __syncthreads();   // staging of tile kt visible to all waves

        // S^T row-tiles: A = K rows (LDS), B = Q regs; then lane-local softmax
        #pragma unroll
        for (int tc = 0; tc < 4; ++tc) {
            short8_t kf0 = *(const short8_t*)&Kbuf[cur][tc * 16 + c][8 * g];
            short8_t kf1 = *(const short8_t*)&Kbuf[cur][tc * 16 + c][32 + 8 * g];
            f32x4 st = {0.f, 0.f, 0.f, 0.f};
            st = __builtin_amdgcn_mfma_f32_16x16x32_bf16(kf0, qf0, st, 0, 0, 0);
            st = __builtin_amdgcn_mfma_f32_16x16x32_bf16(kf1, qf1, st, 0, 0, 0);
            float p0 = __builtin_amdgcn_exp2f(st[0] * sT2);
            float p1 = __builtin_amdgcn_exp2f(st[1] * sT2);
            float p2 = __builtin_amdgcn_exp2f(st[2] * sT2);
            float p3 = __builtin_amdgcn_exp2f(st[3] * sT2);
            lsum += (p0 + p1) + (p2 + p3);
            unsigned u01, u23;
            asm("v_cvt_pk_bf16_f32 %0, %1, %2" : "=v"(u01) : "v"(p0), "v"(p1));
            asm("v_cvt_pk_bf16_f32 %0, %1, %2" : "=v"(u23) : "v"(p2), "v"(p3));
            *(unsigned*)&Pw[(size_t)c * 72 + tc * 16 + 4 * g]     = u01;
            *(unsigned*)&Pw[(size_t)c * 72 + tc * 16 + 4 * g + 2] = u23;
        }
        __builtin_amdgcn_sched_barrier(0);
        // O^T += V^T * P^T (V from LDS, P per-wave LDS)
        #pragma unroll
        for (int ks = 0; ks < 2; ++ks) {
            short8_t vf = *(const short8_t*)&Vbuf[cur][c][ks * 32 + 8 * g];
            short8_t pf = *(const short8_t*)&Pw[(size_t)c * 72 + ks * 32 + 8 * g];
            oacc = __builtin_amdgcn_mfma_f32_16x16x32_bf16(vf, pf, oacc, 0, 0, 0);
        }

        __syncthreads();   // all waves done reading buf[cur]

        if (kt < 31) {     // write next tile into the other buffer
            *(short8_t*)&Kbuf[cur ^ 1][krow][ksub]     = kreg0;
            *(short8_t*)&Kbuf[cur ^ 1][krow][ksub + 8] = kreg1;
            *(uint2*)&Vbuf[cur ^ 1][vrow][vcol] = vreg;
        }
    }

    // full row-sum for q = c: reduce across the 4 lane-groups holding it
    lsum += __shfl_xor(lsum, 16);
    lsum += __shfl_xor(lsum, 32);
    const float inv = 1.0f / lsum;

    // raw-reshape scatter: nn = q-row; row n, cols 256+(nn&3)*16+4g..+3
    const int nn = q0 + c;
    const int n = hh * 512 + (nn >> 2);
    const int cc = 256 + ((nn & 3) << 4) + 4 * g;
    float4 o4 = make_float4(oacc[0] * inv, oacc[1] * inv, oacc[2] * inv, oacc[3] * inv);
    *(float4*)&out[((size_t)b * Nn + n) * 320 + cc] = o4;
}

// ---------------------------------------------------------------------------
extern "C" void kernel_launch(void* const* d_in, const int* in_sizes, int n_in,
                              void* d_out, int out_size, void* d_ws, size_t ws_size,
                              hipStream_t stream)
{
    const float* s     = (const float*)d_in[0];
    const float* h     = (const float*)d_in[1];
    const float* sh    = (const float*)d_in[2];
    const float* temp  = (const float*)d_in[3];
    const float* temp2 = (const float*)d_in[4];
    const float* Wq_c  = (const float*)d_in[5];
    const float* Wq_s  = (const float*)d_in[6];
    const float* Wk_c  = (const float*)d_in[7];
    const float* Wv_c  = (const float*)d_in[8];
    const float* Wk_s  = (const float*)d_in[9];
    const float* Wv_s  = (const float*)d_in[10];
    float* out = (float*)d_out;
    float* ws = (float*)d_ws;

    ushort* sb    = (ushort*)(ws + OFF_SB);
    ushort* shb   = (ushort*)(ws + OFF_SHB);
    ushort* hb    = (ushort*)(ws + OFF_HB);
    ushort* wqcb  = (ushort*)(ws + OFF_WQC);
    ushort* wcatb = (ushort*)(ws + OFF_WCAT);
    ushort* wvsb  = (ushort*)(ws + OFF_WVS);
    ushort* Pqc   = (ushort*)(ws + OFF_PQC);
    ushort* Pqs   = (ushort*)(ws + OFF_PQS);
    ushort* Pkc   = (ushort*)(ws + OFF_PKC);
    ushort* Pvc   = (ushort*)(ws + OFF_PVC);
    ushort* Pks   = (ushort*)(ws + OFF_PKS);
    ushort* PvsT  = (ushort*)(ws + OFF_PVST);
    float*  part  = ws + OFF_PART;
    ushort* Sca   = (ushort*)(ws + OFF_SCA);

    const dim3 blk(256);

    // 1) f32 -> bf16 conversions
    convert_all<<<dim3((SEG8 / 8 + 255) / 256), blk, 0, stream>>>(
        s, sh, h, Wq_c, Wq_s, Wk_c, Wv_c, Wk_s, Wv_s,
        sb, shb, hb, wqcb, wcatb, wvsb);

    // 2) projections (global_load_lds staging)
    mfma_gemm<<<dim3(8, 64), blk, 0, stream>>>(shb, wcatb, Pqs, Pkc, Pvc, Pks, 256);
    mfma_gemm<<<dim3(2, 64), blk, 0, stream>>>(sb, wqcb, Pqc, Pqc, Pqc, Pqc, 256);
    mfma_gemm_vs<<<dim3(32), blk, 0, stream>>>(wvsb, hb, PvsT);

    // 3) channel branch (16 chunks)
    chan_qk_partial<<<dim3(QK_CHUNKS, 4, 4), blk, 0, stream>>>(Pqc, Pkc, part);
    chan_softmax<<<dim3(16), dim3(64), 0, stream>>>(part, temp, Sca);
    chan_pv_mfma<<<dim3(8, 4, 4), blk, 0, stream>>>(Sca, Pvc, out);

    // 4) spatial branch (4-wave blocks, 2 blocks/CU, LDS-staged dbuf)
    spatial_attn8<<<dim3(512), blk, 0, stream>>>(Pqs, Pks, PvsT, temp2, out);
}

// Round 13
// 79.939 us; speedup vs baseline: 1.2219x; 1.2219x over previous
//
#include <hip/hip_runtime.h>
#include <math.h>

// ---------------------------------------------------------------------------
// WCSA round 13 = round 11 (passing, 87.6us) reverted + TWO attributable fixes:
//  (1) spatial: single barrier per KV tile (write prefetch into buf[cur^1]
//      before next iter's barrier; proven race-free) - was 2 barriers.
//  (2) chan_softmax: 256-thread blocks, float4-vectorized partial reads,
//      2-shuffle row max/sum (was 64 serial-scalar threads, latency-bound).
// r12's bundled changes (linear-LDS gemm, 4-wave spatial, 16-chunk QK) all
// REVERTED (regressed +10us, likely LDS bank conflicts in gemm).
// ---------------------------------------------------------------------------

constexpr int Bb = 4, Nn = 2048, Hh = 4;
constexpr int PROJ_EL = Nn * 256;          // elements per batch, 256-col proj
constexpr int HEAD_EL = Nn * 64;           // elements per (b,h) head, d=64

typedef __attribute__((ext_vector_type(8))) short short8_t;   // 8 bf16
typedef __attribute__((ext_vector_type(4))) float f32x4;

__device__ __forceinline__ ushort f2bf(float x) {
    union { float f; unsigned u; } v; v.f = x;
    unsigned r = v.u + 0x7fffu + ((v.u >> 16) & 1u);   // RNE
    return (ushort)(r >> 16);
}
__device__ __forceinline__ float bf2f(ushort x) {
    union { unsigned u; float f; } v; v.u = ((unsigned)x) << 16;
    return v.f;
}

// ---------------- workspace layout (float granularity) ---------------------
constexpr size_t OFF_SB    = 0;                                   // s bf16
constexpr size_t OFF_SHB   = OFF_SB   + 1024 * 1024;              // sh bf16
constexpr size_t OFF_HB    = OFF_SHB  + 1024 * 1024;              // h bf16
constexpr size_t OFF_WQC   = OFF_HB   + 256 * 1024;               // Wq_c bf16
constexpr size_t OFF_WCAT  = OFF_WQC  + 32 * 1024;                // 4x64K el
constexpr size_t OFF_PQC   = OFF_WCAT + 128 * 1024;               // bf16 (8192,256)
constexpr size_t OFF_PQS   = OFF_PQC  + 1024 * 1024;
constexpr size_t OFF_PKC   = OFF_PQS  + 1024 * 1024;
constexpr size_t OFF_PVC   = OFF_PKC  + 1024 * 1024;
constexpr size_t OFF_PKS   = OFF_PVC  + 1024 * 1024;
constexpr size_t OFF_PVST  = OFF_PKS  + 1024 * 1024;              // bf16 (B,H,16,2048)
constexpr size_t OFF_PART  = OFF_PVST + 256 * 1024;               // f32 16*8*4096
constexpr size_t OFF_SCA   = OFF_PART + 512 * 1024;               // bf16 16*4096
constexpr size_t OFF_WVS   = OFF_SCA  + 32 * 1024;                // Wv_s bf16 (64,64)

// ---------------------------------------------------------------------------
// Convert all needed f32 arrays to bf16 in one pass. 8 elements per thread.
// ---------------------------------------------------------------------------
constexpr unsigned SEG0 = 2097152;              // s
constexpr unsigned SEG1 = SEG0 + 2097152;       // sh
constexpr unsigned SEG2 = SEG1 + 524288;        // h
constexpr unsigned SEG3 = SEG2 + 65536;         // Wq_c
constexpr unsigned SEG4 = SEG3 + 65536;         // Wq_s  -> Wcat+0
constexpr unsigned SEG5 = SEG4 + 65536;         // Wk_c  -> Wcat+65536
constexpr unsigned SEG6 = SEG5 + 65536;         // Wv_c  -> Wcat+131072
constexpr unsigned SEG7 = SEG6 + 65536;         // Wk_s  -> Wcat+196608
constexpr unsigned SEG8 = SEG7 + 4096;          // Wv_s

__global__ __launch_bounds__(256) void convert_all(
    const float* __restrict__ s, const float* __restrict__ sh,
    const float* __restrict__ h, const float* __restrict__ wqc,
    const float* __restrict__ wqs, const float* __restrict__ wkc,
    const float* __restrict__ wvc, const float* __restrict__ wks,
    const float* __restrict__ wvs,
    ushort* __restrict__ sb, ushort* __restrict__ shb, ushort* __restrict__ hb,
    ushort* __restrict__ wqcb, ushort* __restrict__ wcatb, ushort* __restrict__ wvsb)
{
    unsigned e = (blockIdx.x * 256u + threadIdx.x) * 8u;
    if (e >= SEG8) return;
    const float* src; ushort* dst; unsigned off;
    if      (e < SEG0) { src = s;   dst = sb;             off = e; }
    else if (e < SEG1) { src = sh;  dst = shb;            off = e - SEG0; }
    else if (e < SEG2) { src = h;   dst = hb;             off = e - SEG1; }
    else if (e < SEG3) { src = wqc; dst = wqcb;           off = e - SEG2; }
    else if (e < SEG4) { src = wqs; dst = wcatb;          off = e - SEG3; }
    else if (e < SEG5) { src = wkc; dst = wcatb + 65536;  off = e - SEG4; }
    else if (e < SEG6) { src = wvc; dst = wcatb + 131072; off = e - SEG5; }
    else if (e < SEG7) { src = wks; dst = wcatb + 196608; off = e - SEG6; }
    else               { src = wvs; dst = wvsb;           off = e - SEG7; }
    float4 f0 = *(const float4*)&src[off];
    float4 f1 = *(const float4*)&src[off + 4];
    short8_t o;
    o[0] = f2bf(f0.x); o[1] = f2bf(f0.y); o[2] = f2bf(f0.z); o[3] = f2bf(f0.w);
    o[4] = f2bf(f1.x); o[5] = f2bf(f1.y); o[6] = f2bf(f1.z); o[7] = f2bf(f1.w);
    *(short8_t*)&dst[off] = o;
}

// ---------------------------------------------------------------------------
// bf16 MFMA GEMM (r11 version, verified): padded-LDS reg staging.
// C = X(M,K) @ W(Ntot,K)^T, bf16 out, segment-routed. 128x128 tile, BK=64.
// ---------------------------------------------------------------------------
__global__ __launch_bounds__(256) void mfma_gemm(
    const ushort* __restrict__ X, const ushort* __restrict__ W,
    ushort* __restrict__ d0, ushort* __restrict__ d1,
    ushort* __restrict__ d2, ushort* __restrict__ d3, int K)
{
    __shared__ ushort Xs[128][72];
    __shared__ ushort Ws[128][72];
    const int t = threadIdx.x;
    const int w = t >> 6, l = t & 63, c = l & 15, g = l >> 4;
    const int wr = w >> 1, wc = w & 1;
    const int m0 = blockIdx.y * 128, n0 = blockIdx.x * 128;

    f32x4 acc[4][4] = {};

    const int srow = t >> 2, scs = (t & 3) * 16;
    for (int k0 = 0; k0 < K; k0 += 64) {
        __syncthreads();
        #pragma unroll
        for (int p = 0; p < 2; ++p) {
            const ushort* xs = &X[(size_t)(m0 + p * 64 + srow) * K + k0 + scs];
            *(short8_t*)&Xs[p * 64 + srow][scs]     = *(const short8_t*)xs;
            *(short8_t*)&Xs[p * 64 + srow][scs + 8] = *(const short8_t*)(xs + 8);
            const ushort* wsp = &W[(size_t)(n0 + p * 64 + srow) * K + k0 + scs];
            *(short8_t*)&Ws[p * 64 + srow][scs]     = *(const short8_t*)wsp;
            *(short8_t*)&Ws[p * 64 + srow][scs + 8] = *(const short8_t*)(wsp + 8);
        }
        __syncthreads();
        #pragma unroll
        for (int ks = 0; ks < 2; ++ks) {
            short8_t af[4], bf[4];
            #pragma unroll
            for (int rt = 0; rt < 4; ++rt)
                af[rt] = *(const short8_t*)&Xs[wr * 64 + rt * 16 + c][ks * 32 + 8 * g];
            #pragma unroll
            for (int ct = 0; ct < 4; ++ct)
                bf[ct] = *(const short8_t*)&Ws[wc * 64 + ct * 16 + c][ks * 32 + 8 * g];
            #pragma unroll
            for (int rt = 0; rt < 4; ++rt)
                #pragma unroll
                for (int ct = 0; ct < 4; ++ct)
                    acc[rt][ct] = __builtin_amdgcn_mfma_f32_16x16x32_bf16(
                        af[rt], bf[ct], acc[rt][ct], 0, 0, 0);
        }
    }

    const int seg = n0 >> 8;
    ushort* dst = seg == 0 ? d0 : seg == 1 ? d1 : seg == 2 ? d2 : d3;
    const int colbase = (n0 & 255) + wc * 64;
    #pragma unroll
    for (int rt = 0; rt < 4; ++rt)
        #pragma unroll
        for (int ct = 0; ct < 4; ++ct)
            #pragma unroll
            for (int r = 0; r < 4; ++r) {
                int mrow = m0 + wr * 64 + rt * 16 + 4 * g + r;
                int col = colbase + ct * 16 + c;
                dst[(size_t)mrow * 256 + col] = f2bf(acc[rt][ct][r]);
            }
}

// ---------------------------------------------------------------------------
// v_s^T producer with raw-reshape-aware scatter (verified round 6).
// ---------------------------------------------------------------------------
__global__ __launch_bounds__(256) void mfma_gemm_vs(
    const ushort* __restrict__ Wvs, const ushort* __restrict__ Hb,
    ushort* __restrict__ Cvt)
{
    const int t = threadIdx.x;
    const int w = t >> 6, l = t & 63, c = l & 15, g = l >> 4;
    const int n0 = blockIdx.x * 256 + w * 64;

    f32x4 acc[4][4] = {};
    #pragma unroll
    for (int ks = 0; ks < 2; ++ks) {
        short8_t af[4], bfr[4];
        #pragma unroll
        for (int rt = 0; rt < 4; ++rt)
            af[rt] = *(const short8_t*)&Wvs[(size_t)(rt * 16 + c) * 64 + ks * 32 + 8 * g];
        #pragma unroll
        for (int ct = 0; ct < 4; ++ct)
            bfr[ct] = *(const short8_t*)&Hb[(size_t)(n0 + ct * 16 + c) * 64 + ks * 32 + 8 * g];
        #pragma unroll
        for (int rt = 0; rt < 4; ++rt)
            #pragma unroll
            for (int ct = 0; ct < 4; ++ct)
                acc[rt][ct] = __builtin_amdgcn_mfma_f32_16x16x32_bf16(
                    af[rt], bfr[ct], acc[rt][ct], 0, 0, 0);
    }
    #pragma unroll
    for (int rt = 0; rt < 4; ++rt)
        #pragma unroll
        for (int ct = 0; ct < 4; ++ct)
            #pragma unroll
            for (int r = 0; r < 4; ++r) {
                int cc = rt * 16 + 4 * g + r;       // output channel 0..63
                int m  = n0 + ct * 16 + c;          // global row 0..8191
                int b  = m >> 11, n = m & 2047;
                int L  = n * 64 + cc;               // within-batch flat index
                int hh = L >> 15;
                int k  = (L & 32767) >> 4;
                int d  = L & 15;
                Cvt[(size_t)((b * 4 + hh) * 16 + d) * 2048 + k] = f2bf(acc[rt][ct][r]);
            }
}

// ---------------------------------------------------------------------------
// Channel stage 1 (f32 compute, bf16 input) — r11 version (verified).
// ---------------------------------------------------------------------------
__global__ __launch_bounds__(256) void chan_qk_partial(const ushort* __restrict__ Pqc,
                                                       const ushort* __restrict__ Pkc,
                                                       float* __restrict__ part)
{
    const int ch = blockIdx.x, hh = blockIdx.y, b = blockIdx.z;
    const ushort* Q = Pqc + (size_t)b * PROJ_EL + (size_t)hh * HEAD_EL;
    const ushort* Kk = Pkc + (size_t)b * PROJ_EL + (size_t)hh * HEAD_EL;
    __shared__ float Qs[64][68], Ks[64][68];
    const int t = threadIdx.x, ty = t >> 4, tx = t & 15;

    float acc[4][4] = {};
    for (int sub = 0; sub < 4; ++sub) {
        const int r0 = ch * 256 + sub * 64;
        __syncthreads();
        #pragma unroll
        for (int q = t; q < 512; q += 256) {
            int row = q >> 3, c8 = (q & 7) * 8;
            short8_t qv = *(const short8_t*)&Q[(size_t)(r0 + row) * 64 + c8];
            short8_t kv = *(const short8_t*)&Kk[(size_t)(r0 + row) * 64 + c8];
            #pragma unroll
            for (int j = 0; j < 8; ++j) {
                Qs[row][c8 + j] = bf2f((ushort)qv[j]);
                Ks[row][c8 + j] = bf2f((ushort)kv[j]);
            }
        }
        __syncthreads();
        #pragma unroll 8
        for (int nn = 0; nn < 64; ++nn) {
            float4 q4 = *(const float4*)&Qs[nn][ty * 4];
            float4 k4 = *(const float4*)&Ks[nn][tx * 4];
            float qa[4] = {q4.x, q4.y, q4.z, q4.w};
            float ka[4] = {k4.x, k4.y, k4.z, k4.w};
            #pragma unroll
            for (int ii = 0; ii < 4; ++ii)
                #pragma unroll
                for (int jj = 0; jj < 4; ++jj)
                    acc[ii][jj] += qa[ii] * ka[jj];
        }
    }
    float* P = part + (((size_t)(b * 4 + hh) * 8 + ch) << 12);
    #pragma unroll
    for (int ii = 0; ii < 4; ++ii)
        *(float4*)&P[(ty * 4 + ii) * 64 + tx * 4] =
            make_float4(acc[ii][0], acc[ii][1], acc[ii][2], acc[ii][3]);
}

// ---------------------------------------------------------------------------
// Channel stage 2, round 13: 256-thread blocks, vectorized. Thread = (row
// i = t>>2, col-quarter q = t&3, 16 cols). float4 partial reads; row max and
// row sum via 2 x __shfl_xor over the 4-lane quarter group.
// ---------------------------------------------------------------------------
__global__ __launch_bounds__(256) void chan_softmax(const float* __restrict__ part,
                                                    const float* __restrict__ temp,
                                                    ushort* __restrict__ Sca)
{
    const int bh = blockIdx.x;
    const int hsel = bh & 3;
    const int t = threadIdx.x;
    const int i = t >> 2, q = t & 3;
    const float sT = 0.125f * temp[hsel];

    float v[16];
    #pragma unroll
    for (int jj = 0; jj < 16; ++jj) v[jj] = 0.f;
    #pragma unroll
    for (int cc = 0; cc < 8; ++cc) {
        const float* p = &part[((size_t)bh * 8 + cc) * 4096 + i * 64 + q * 16];
        #pragma unroll
        for (int j4 = 0; j4 < 4; ++j4) {
            float4 f = *(const float4*)&p[j4 * 4];
            v[j4 * 4 + 0] += f.x; v[j4 * 4 + 1] += f.y;
            v[j4 * 4 + 2] += f.z; v[j4 * 4 + 3] += f.w;
        }
    }
    float m = -1e30f;
    #pragma unroll
    for (int jj = 0; jj < 16; ++jj) { v[jj] *= sT; m = fmaxf(m, v[jj]); }
    m = fmaxf(m, __shfl_xor(m, 1, 4));
    m = fmaxf(m, __shfl_xor(m, 2, 4));
    float sum = 0.f;
    #pragma unroll
    for (int jj = 0; jj < 16; ++jj) { v[jj] = __expf(v[jj] - m); sum += v[jj]; }
    sum += __shfl_xor(sum, 1, 4);
    sum += __shfl_xor(sum, 2, 4);
    const float inv = 1.0f / sum;
    ushort* dst = &Sca[((size_t)bh << 12) + i * 64 + q * 16];
    #pragma unroll
    for (int j4 = 0; j4 < 4; ++j4) {
        ushort4 r;
        r.x = f2bf(v[j4 * 4 + 0] * inv); r.y = f2bf(v[j4 * 4 + 1] * inv);
        r.z = f2bf(v[j4 * 4 + 2] * inv); r.w = f2bf(v[j4 * 4 + 3] * inv);
        *(ushort4*)&dst[j4 * 4] = r;
    }
}

// ---------------------------------------------------------------------------
// Channel stage 3 via MFMA — unchanged from round 3 (verified).
// ---------------------------------------------------------------------------
__global__ __launch_bounds__(256) void chan_pv_mfma(const ushort* __restrict__ Sca,
                                                    const ushort* __restrict__ Pvc,
                                                    float* __restrict__ out)
{
    const int nc = blockIdx.x, hh = blockIdx.y, b = blockIdx.z;
    const int t = threadIdx.x;
    const int w = t >> 6, l = t & 63, c = l & 15, g = l >> 4;

    const ushort* S = Sca + ((size_t)(b * 4 + hh) << 12);
    const ushort* V = Pvc + (size_t)b * PROJ_EL + (size_t)hh * HEAD_EL;
    const int n0w = nc * 256 + w * 64;

    f32x4 acc[4][4] = {};
    #pragma unroll
    for (int ks = 0; ks < 2; ++ks) {
        short8_t af[4], bfr[4];
        #pragma unroll
        for (int rt = 0; rt < 4; ++rt)
            af[rt] = *(const short8_t*)&S[(size_t)(rt * 16 + c) * 64 + ks * 32 + 8 * g];
        #pragma unroll
        for (int ct = 0; ct < 4; ++ct)
            bfr[ct] = *(const short8_t*)&V[(size_t)(n0w + ct * 16 + c) * 64 + ks * 32 + 8 * g];
        #pragma unroll
        for (int rt = 0; rt < 4; ++rt)
            #pragma unroll
            for (int ct = 0; ct < 4; ++ct)
                acc[rt][ct] = __builtin_amdgcn_mfma_f32_16x16x32_bf16(
                    af[rt], bfr[ct], acc[rt][ct], 0, 0, 0);
    }

    float* ob = out + (size_t)b * (Nn * 320);
    #pragma unroll
    for (int rt = 0; rt < 4; ++rt)
        #pragma unroll
        for (int ct = 0; ct < 4; ++ct)
            #pragma unroll
            for (int r = 0; r < 4; ++r) {
                int i = rt * 16 + 4 * g + r;
                int nn = n0w + ct * 16 + c;
                int rem = hh * 131072 + i * 2048 + nn;
                ob[(rem >> 8) * 320 + (rem & 255)] = acc[rt][ct][r];
            }
}

// ---------------------------------------------------------------------------
// Spatial attention, round 13 = r11 kernel with SINGLE barrier per KV tile.
// 256 blocks (XCD-decoded: 2 heads/XCD) x 512 thr = 8 waves; 128 q-rows per
// block. Loop: issue next-tile global loads -> barrier -> compute from
// buf[cur] -> write prefetched regs to buf[cur^1]. Race-free: the write
// targets the buffer nobody reads this iteration, and prior-iteration reads
// of it completed before the barrier the writer already passed.
// Math identical to r11 (verified).
// ---------------------------------------------------------------------------
__global__ __launch_bounds__(512, 2) void spatial_attn9(
    const ushort* __restrict__ Pqs, const ushort* __restrict__ Pks,
    const ushort* __restrict__ PvsT, const float* __restrict__ temp2,
    float* __restrict__ out)
{
    // XCD-aware decode: 256 blocks; xcd = i&7 serves heads xcd and xcd+8
    const int i0 = blockIdx.x;
    const int xcd = i0 & 7, j = i0 >> 3;       // j in [0,32)
    const int hsel = xcd + 8 * (j & 1);        // 0..15 = b*4+hh
    const int qb = j >> 1;                     // 0..15
    const int b = hsel >> 2, hh = hsel & 3;

    const int t = threadIdx.x, w = t >> 6, l = t & 63;
    const int c = l & 15, g = l >> 4;

    __shared__ ushort Kbuf[2][64][72];         // 18.4 KB
    __shared__ ushort Vbuf[2][16][72];         //  4.6 KB
    __shared__ ushort P_lds[8][16][72];        // 18.4 KB (per-wave P tile)

    const ushort* Qh = Pqs + (size_t)b * PROJ_EL + (size_t)hh * HEAD_EL;
    const ushort* Kh = Pks + (size_t)b * PROJ_EL + (size_t)hh * HEAD_EL;
    const ushort* Vt = PvsT + (size_t)((b * 4 + hh) * 16) * 2048;   // (16, 2048)
    const float sT2 = 0.125f * temp2[hh] * 1.44269504f;   // fold log2(e)

    const int q0 = qb * 128 + w * 16;
    const ushort* qp = Qh + (size_t)(q0 + c) * 64 + 8 * g;
    const short8_t qf0 = *(const short8_t*)qp;
    const short8_t qf1 = *(const short8_t*)(qp + 32);

    f32x4 oacc = {0.f, 0.f, 0.f, 0.f};
    float lsum = 0.f;
    ushort* Pw = &P_lds[w][0][0];              // row stride 72 ushorts

    // staging geometry: K 8KB -> 512 thr x 16B; V 2KB -> 512 thr x 4B
    const int krow = t >> 3, ksub = (t & 7) * 8;
    const int vrow = t >> 5, vcol = (t & 31) * 2;

    // prologue: stage tile 0 into buffer 0
    short8_t kreg = *(const short8_t*)&Kh[(size_t)krow * 64 + ksub];
    uint vreg = *(const uint*)&Vt[(size_t)vrow * 2048 + vcol];
    *(short8_t*)&Kbuf[0][krow][ksub] = kreg;
    *(uint*)&Vbuf[0][vrow][vcol] = vreg;

    for (int kt = 0; kt < 32; ++kt) {
        const int kb = kt * 64;
        const int cur = kt & 1;

        // issue next tile's global loads; consumed at the bottom of this iter
        if (kt < 31) {
            kreg = *(const short8_t*)&Kh[(size_t)(kb + 64 + krow) * 64 + ksub];
            vreg = *(const uint*)&Vt[(size_t)vrow * 2048 + kb + 64 + vcol];
        }

        __syncthreads();   // buf[cur] (written last iter / prologue) visible

        // S^T row-tiles: A = K rows (LDS), B = Q regs; then lane-local softmax
        #pragma unroll
        for (int tc = 0; tc < 4; ++tc) {
            short8_t kf0 = *(const short8_t*)&Kbuf[cur][tc * 16 + c][8 * g];
            short8_t kf1 = *(const short8_t*)&Kbuf[cur][tc * 16 + c][32 + 8 * g];
            f32x4 st = {0.f, 0.f, 0.f, 0.f};
            st = __builtin_amdgcn_mfma_f32_16x16x32_bf16(kf0, qf0, st, 0, 0, 0);
            st = __builtin_amdgcn_mfma_f32_16x16x32_bf16(kf1, qf1, st, 0, 0, 0);
            float p0 = __builtin_amdgcn_exp2f(st[0] * sT2);
            float p1 = __builtin_amdgcn_exp2f(st[1] * sT2);
            float p2 = __builtin_amdgcn_exp2f(st[2] * sT2);
            float p3 = __builtin_amdgcn_exp2f(st[3] * sT2);
            lsum += (p0 + p1) + (p2 + p3);
            unsigned u01, u23;
            asm("v_cvt_pk_bf16_f32 %0, %1, %2" : "=v"(u01) : "v"(p0), "v"(p1));
            asm("v_cvt_pk_bf16_f32 %0, %1, %2" : "=v"(u23) : "v"(p2), "v"(p3));
            *(unsigned*)&Pw[(size_t)c * 72 + tc * 16 + 4 * g]     = u01;
            *(unsigned*)&Pw[(size_t)c * 72 + tc * 16 + 4 * g + 2] = u23;
        }
        __builtin_amdgcn_sched_barrier(0);
        // O^T += V^T * P^T (V from LDS, P per-wave LDS)
        #pragma unroll
        for (int ks = 0; ks < 2; ++ks) {
            short8_t vf = *(const short8_t*)&Vbuf[cur][c][ks * 32 + 8 * g];
            short8_t pf = *(const short8_t*)&Pw[(size_t)c * 72 + ks * 32 + 8 * g];
            oacc = __builtin_amdgcn_mfma_f32_16x16x32_bf16(vf, pf, oacc, 0, 0, 0);
        }

        // write next tile into the other buffer (nobody reads it this iter)
        if (kt < 31) {
            *(short8_t*)&Kbuf[cur ^ 1][krow][ksub] = kreg;
            *(uint*)&Vbuf[cur ^ 1][vrow][vcol] = vreg;
        }
    }

    // full row-sum for q = c: reduce across the 4 lane-groups holding it
    lsum += __shfl_xor(lsum, 16);
    lsum += __shfl_xor(lsum, 32);
    const float inv = 1.0f / lsum;

    // raw-reshape scatter: nn = q-row; row n, cols 256+(nn&3)*16+4g..+3
    const int nn = q0 + c;
    const int n = hh * 512 + (nn >> 2);
    const int cc = 256 + ((nn & 3) << 4) + 4 * g;
    float4 o4 = make_float4(oacc[0] * inv, oacc[1] * inv, oacc[2] * inv, oacc[3] * inv);
    *(float4*)&out[((size_t)b * Nn + n) * 320 + cc] = o4;
}

// ---------------------------------------------------------------------------
extern "C" void kernel_launch(void* const* d_in, const int* in_sizes, int n_in,
                              void* d_out, int out_size, void* d_ws, size_t ws_size,
                              hipStream_t stream)
{
    const float* s     = (const float*)d_in[0];
    const float* h     = (const float*)d_in[1];
    const float* sh    = (const float*)d_in[2];
    const float* temp  = (const float*)d_in[3];
    const float* temp2 = (const float*)d_in[4];
    const float* Wq_c  = (const float*)d_in[5];
    const float* Wq_s  = (const float*)d_in[6];
    const float* Wk_c  = (const float*)d_in[7];
    const float* Wv_c  = (const float*)d_in[8];
    const float* Wk_s  = (const float*)d_in[9];
    const float* Wv_s  = (const float*)d_in[10];
    float* out = (float*)d_out;
    float* ws = (float*)d_ws;

    ushort* sb    = (ushort*)(ws + OFF_SB);
    ushort* shb   = (ushort*)(ws + OFF_SHB);
    ushort* hb    = (ushort*)(ws + OFF_HB);
    ushort* wqcb  = (ushort*)(ws + OFF_WQC);
    ushort* wcatb = (ushort*)(ws + OFF_WCAT);
    ushort* wvsb  = (ushort*)(ws + OFF_WVS);
    ushort* Pqc   = (ushort*)(ws + OFF_PQC);
    ushort* Pqs   = (ushort*)(ws + OFF_PQS);
    ushort* Pkc   = (ushort*)(ws + OFF_PKC);
    ushort* Pvc   = (ushort*)(ws + OFF_PVC);
    ushort* Pks   = (ushort*)(ws + OFF_PKS);
    ushort* PvsT  = (ushort*)(ws + OFF_PVST);
    float*  part  = ws + OFF_PART;
    ushort* Sca   = (ushort*)(ws + OFF_SCA);

    const dim3 blk(256);

    // 1) f32 -> bf16 conversions
    convert_all<<<dim3((SEG8 / 8 + 255) / 256), blk, 0, stream>>>(
        s, sh, h, Wq_c, Wq_s, Wk_c, Wv_c, Wk_s, Wv_s,
        sb, shb, hb, wqcb, wcatb, wvsb);

    // 2) projections
    mfma_gemm<<<dim3(8, 64), blk, 0, stream>>>(shb, wcatb, Pqs, Pkc, Pvc, Pks, 256);
    mfma_gemm<<<dim3(2, 64), blk, 0, stream>>>(sb, wqcb, Pqc, Pqc, Pqc, Pqc, 256);
    mfma_gemm_vs<<<dim3(32), blk, 0, stream>>>(wvsb, hb, PvsT);

    // 3) channel branch
    chan_qk_partial<<<dim3(8, 4, 4), blk, 0, stream>>>(Pqc, Pkc, part);
    chan_softmax<<<dim3(16), blk, 0, stream>>>(part, temp, Sca);
    chan_pv_mfma<<<dim3(8, 4, 4), blk, 0, stream>>>(Sca, Pvc, out);

    // 4) spatial branch (single-barrier LDS double-buffer)
    spatial_attn9<<<dim3(256), dim3(512), 0, stream>>>(Pqs, Pks, PvsT, temp2, out);
}

// Round 14
// 76.160 us; speedup vs baseline: 1.2825x; 1.0496x over previous
//
#include <hip/hip_runtime.h>
#include <math.h>

// ---------------------------------------------------------------------------
// WCSA round 14 = round 13 (passing, 79.9us) + ONE change: spatial waves
// re-partitioned 4 q-groups x 2 KV-halves, 2 q-subtiles per wave sharing K
// fragments (LDS reads per unit work 12 -> 7; theory: kernel is LDS-read-
// pipe-bound at ~18us). Split-KV halves combine additively (r7-verified).
// Staging/barrier structure identical to r13. All other kernels unchanged.
// ---------------------------------------------------------------------------

constexpr int Bb = 4, Nn = 2048, Hh = 4;
constexpr int PROJ_EL = Nn * 256;          // elements per batch, 256-col proj
constexpr int HEAD_EL = Nn * 64;           // elements per (b,h) head, d=64

typedef __attribute__((ext_vector_type(8))) short short8_t;   // 8 bf16
typedef __attribute__((ext_vector_type(4))) float f32x4;

__device__ __forceinline__ ushort f2bf(float x) {
    union { float f; unsigned u; } v; v.f = x;
    unsigned r = v.u + 0x7fffu + ((v.u >> 16) & 1u);   // RNE
    return (ushort)(r >> 16);
}
__device__ __forceinline__ float bf2f(ushort x) {
    union { unsigned u; float f; } v; v.u = ((unsigned)x) << 16;
    return v.f;
}

// ---------------- workspace layout (float granularity) ---------------------
constexpr size_t OFF_SB    = 0;                                   // s bf16
constexpr size_t OFF_SHB   = OFF_SB   + 1024 * 1024;              // sh bf16
constexpr size_t OFF_HB    = OFF_SHB  + 1024 * 1024;              // h bf16
constexpr size_t OFF_WQC   = OFF_HB   + 256 * 1024;               // Wq_c bf16
constexpr size_t OFF_WCAT  = OFF_WQC  + 32 * 1024;                // 4x64K el
constexpr size_t OFF_PQC   = OFF_WCAT + 128 * 1024;               // bf16 (8192,256)
constexpr size_t OFF_PQS   = OFF_PQC  + 1024 * 1024;
constexpr size_t OFF_PKC   = OFF_PQS  + 1024 * 1024;
constexpr size_t OFF_PVC   = OFF_PKC  + 1024 * 1024;
constexpr size_t OFF_PKS   = OFF_PVC  + 1024 * 1024;
constexpr size_t OFF_PVST  = OFF_PKS  + 1024 * 1024;              // bf16 (B,H,16,2048)
constexpr size_t OFF_PART  = OFF_PVST + 256 * 1024;               // f32 16*8*4096
constexpr size_t OFF_SCA   = OFF_PART + 512 * 1024;               // bf16 16*4096
constexpr size_t OFF_WVS   = OFF_SCA  + 32 * 1024;                // Wv_s bf16 (64,64)

// ---------------------------------------------------------------------------
// Convert all needed f32 arrays to bf16 in one pass. 8 elements per thread.
// ---------------------------------------------------------------------------
constexpr unsigned SEG0 = 2097152;              // s
constexpr unsigned SEG1 = SEG0 + 2097152;       // sh
constexpr unsigned SEG2 = SEG1 + 524288;        // h
constexpr unsigned SEG3 = SEG2 + 65536;         // Wq_c
constexpr unsigned SEG4 = SEG3 + 65536;         // Wq_s  -> Wcat+0
constexpr unsigned SEG5 = SEG4 + 65536;         // Wk_c  -> Wcat+65536
constexpr unsigned SEG6 = SEG5 + 65536;         // Wv_c  -> Wcat+131072
constexpr unsigned SEG7 = SEG6 + 65536;         // Wk_s  -> Wcat+196608
constexpr unsigned SEG8 = SEG7 + 4096;          // Wv_s

__global__ __launch_bounds__(256) void convert_all(
    const float* __restrict__ s, const float* __restrict__ sh,
    const float* __restrict__ h, const float* __restrict__ wqc,
    const float* __restrict__ wqs, const float* __restrict__ wkc,
    const float* __restrict__ wvc, const float* __restrict__ wks,
    const float* __restrict__ wvs,
    ushort* __restrict__ sb, ushort* __restrict__ shb, ushort* __restrict__ hb,
    ushort* __restrict__ wqcb, ushort* __restrict__ wcatb, ushort* __restrict__ wvsb)
{
    unsigned e = (blockIdx.x * 256u + threadIdx.x) * 8u;
    if (e >= SEG8) return;
    const float* src; ushort* dst; unsigned off;
    if      (e < SEG0) { src = s;   dst = sb;             off = e; }
    else if (e < SEG1) { src = sh;  dst = shb;            off = e - SEG0; }
    else if (e < SEG2) { src = h;   dst = hb;             off = e - SEG1; }
    else if (e < SEG3) { src = wqc; dst = wqcb;           off = e - SEG2; }
    else if (e < SEG4) { src = wqs; dst = wcatb;          off = e - SEG3; }
    else if (e < SEG5) { src = wkc; dst = wcatb + 65536;  off = e - SEG4; }
    else if (e < SEG6) { src = wvc; dst = wcatb + 131072; off = e - SEG5; }
    else if (e < SEG7) { src = wks; dst = wcatb + 196608; off = e - SEG6; }
    else               { src = wvs; dst = wvsb;           off = e - SEG7; }
    float4 f0 = *(const float4*)&src[off];
    float4 f1 = *(const float4*)&src[off + 4];
    short8_t o;
    o[0] = f2bf(f0.x); o[1] = f2bf(f0.y); o[2] = f2bf(f0.z); o[3] = f2bf(f0.w);
    o[4] = f2bf(f1.x); o[5] = f2bf(f1.y); o[6] = f2bf(f1.z); o[7] = f2bf(f1.w);
    *(short8_t*)&dst[off] = o;
}

// ---------------------------------------------------------------------------
// bf16 MFMA GEMM (r11 version, verified): padded-LDS reg staging.
// ---------------------------------------------------------------------------
__global__ __launch_bounds__(256) void mfma_gemm(
    const ushort* __restrict__ X, const ushort* __restrict__ W,
    ushort* __restrict__ d0, ushort* __restrict__ d1,
    ushort* __restrict__ d2, ushort* __restrict__ d3, int K)
{
    __shared__ ushort Xs[128][72];
    __shared__ ushort Ws[128][72];
    const int t = threadIdx.x;
    const int w = t >> 6, l = t & 63, c = l & 15, g = l >> 4;
    const int wr = w >> 1, wc = w & 1;
    const int m0 = blockIdx.y * 128, n0 = blockIdx.x * 128;

    f32x4 acc[4][4] = {};

    const int srow = t >> 2, scs = (t & 3) * 16;
    for (int k0 = 0; k0 < K; k0 += 64) {
        __syncthreads();
        #pragma unroll
        for (int p = 0; p < 2; ++p) {
            const ushort* xs = &X[(size_t)(m0 + p * 64 + srow) * K + k0 + scs];
            *(short8_t*)&Xs[p * 64 + srow][scs]     = *(const short8_t*)xs;
            *(short8_t*)&Xs[p * 64 + srow][scs + 8] = *(const short8_t*)(xs + 8);
            const ushort* wsp = &W[(size_t)(n0 + p * 64 + srow) * K + k0 + scs];
            *(short8_t*)&Ws[p * 64 + srow][scs]     = *(const short8_t*)wsp;
            *(short8_t*)&Ws[p * 64 + srow][scs + 8] = *(const short8_t*)(wsp + 8);
        }
        __syncthreads();
        #pragma unroll
        for (int ks = 0; ks < 2; ++ks) {
            short8_t af[4], bf[4];
            #pragma unroll
            for (int rt = 0; rt < 4; ++rt)
                af[rt] = *(const short8_t*)&Xs[wr * 64 + rt * 16 + c][ks * 32 + 8 * g];
            #pragma unroll
            for (int ct = 0; ct < 4; ++ct)
                bf[ct] = *(const short8_t*)&Ws[wc * 64 + ct * 16 + c][ks * 32 + 8 * g];
            #pragma unroll
            for (int rt = 0; rt < 4; ++rt)
                #pragma unroll
                for (int ct = 0; ct < 4; ++ct)
                    acc[rt][ct] = __builtin_amdgcn_mfma_f32_16x16x32_bf16(
                        af[rt], bf[ct], acc[rt][ct], 0, 0, 0);
        }
    }

    const int seg = n0 >> 8;
    ushort* dst = seg == 0 ? d0 : seg == 1 ? d1 : seg == 2 ? d2 : d3;
    const int colbase = (n0 & 255) + wc * 64;
    #pragma unroll
    for (int rt = 0; rt < 4; ++rt)
        #pragma unroll
        for (int ct = 0; ct < 4; ++ct)
            #pragma unroll
            for (int r = 0; r < 4; ++r) {
                int mrow = m0 + wr * 64 + rt * 16 + 4 * g + r;
                int col = colbase + ct * 16 + c;
                dst[(size_t)mrow * 256 + col] = f2bf(acc[rt][ct][r]);
            }
}

// ---------------------------------------------------------------------------
// v_s^T producer with raw-reshape-aware scatter (verified round 6).
// ---------------------------------------------------------------------------
__global__ __launch_bounds__(256) void mfma_gemm_vs(
    const ushort* __restrict__ Wvs, const ushort* __restrict__ Hb,
    ushort* __restrict__ Cvt)
{
    const int t = threadIdx.x;
    const int w = t >> 6, l = t & 63, c = l & 15, g = l >> 4;
    const int n0 = blockIdx.x * 256 + w * 64;

    f32x4 acc[4][4] = {};
    #pragma unroll
    for (int ks = 0; ks < 2; ++ks) {
        short8_t af[4], bfr[4];
        #pragma unroll
        for (int rt = 0; rt < 4; ++rt)
            af[rt] = *(const short8_t*)&Wvs[(size_t)(rt * 16 + c) * 64 + ks * 32 + 8 * g];
        #pragma unroll
        for (int ct = 0; ct < 4; ++ct)
            bfr[ct] = *(const short8_t*)&Hb[(size_t)(n0 + ct * 16 + c) * 64 + ks * 32 + 8 * g];
        #pragma unroll
        for (int rt = 0; rt < 4; ++rt)
            #pragma unroll
            for (int ct = 0; ct < 4; ++ct)
                acc[rt][ct] = __builtin_amdgcn_mfma_f32_16x16x32_bf16(
                    af[rt], bfr[ct], acc[rt][ct], 0, 0, 0);
    }
    #pragma unroll
    for (int rt = 0; rt < 4; ++rt)
        #pragma unroll
        for (int ct = 0; ct < 4; ++ct)
            #pragma unroll
            for (int r = 0; r < 4; ++r) {
                int cc = rt * 16 + 4 * g + r;       // output channel 0..63
                int m  = n0 + ct * 16 + c;          // global row 0..8191
                int b  = m >> 11, n = m & 2047;
                int L  = n * 64 + cc;               // within-batch flat index
                int hh = L >> 15;
                int k  = (L & 32767) >> 4;
                int d  = L & 15;
                Cvt[(size_t)((b * 4 + hh) * 16 + d) * 2048 + k] = f2bf(acc[rt][ct][r]);
            }
}

// ---------------------------------------------------------------------------
// Channel stage 1 (f32 compute, bf16 input) — r11 version (verified).
// ---------------------------------------------------------------------------
__global__ __launch_bounds__(256) void chan_qk_partial(const ushort* __restrict__ Pqc,
                                                       const ushort* __restrict__ Pkc,
                                                       float* __restrict__ part)
{
    const int ch = blockIdx.x, hh = blockIdx.y, b = blockIdx.z;
    const ushort* Q = Pqc + (size_t)b * PROJ_EL + (size_t)hh * HEAD_EL;
    const ushort* Kk = Pkc + (size_t)b * PROJ_EL + (size_t)hh * HEAD_EL;
    __shared__ float Qs[64][68], Ks[64][68];
    const int t = threadIdx.x, ty = t >> 4, tx = t & 15;

    float acc[4][4] = {};
    for (int sub = 0; sub < 4; ++sub) {
        const int r0 = ch * 256 + sub * 64;
        __syncthreads();
        #pragma unroll
        for (int q = t; q < 512; q += 256) {
            int row = q >> 3, c8 = (q & 7) * 8;
            short8_t qv = *(const short8_t*)&Q[(size_t)(r0 + row) * 64 + c8];
            short8_t kv = *(const short8_t*)&Kk[(size_t)(r0 + row) * 64 + c8];
            #pragma unroll
            for (int j = 0; j < 8; ++j) {
                Qs[row][c8 + j] = bf2f((ushort)qv[j]);
                Ks[row][c8 + j] = bf2f((ushort)kv[j]);
            }
        }
        __syncthreads();
        #pragma unroll 8
        for (int nn = 0; nn < 64; ++nn) {
            float4 q4 = *(const float4*)&Qs[nn][ty * 4];
            float4 k4 = *(const float4*)&Ks[nn][tx * 4];
            float qa[4] = {q4.x, q4.y, q4.z, q4.w};
            float ka[4] = {k4.x, k4.y, k4.z, k4.w};
            #pragma unroll
            for (int ii = 0; ii < 4; ++ii)
                #pragma unroll
                for (int jj = 0; jj < 4; ++jj)
                    acc[ii][jj] += qa[ii] * ka[jj];
        }
    }
    float* P = part + (((size_t)(b * 4 + hh) * 8 + ch) << 12);
    #pragma unroll
    for (int ii = 0; ii < 4; ++ii)
        *(float4*)&P[(ty * 4 + ii) * 64 + tx * 4] =
            make_float4(acc[ii][0], acc[ii][1], acc[ii][2], acc[ii][3]);
}

// ---------------------------------------------------------------------------
// Channel stage 2 — r13 vectorized version (verified).
// ---------------------------------------------------------------------------
__global__ __launch_bounds__(256) void chan_softmax(const float* __restrict__ part,
                                                    const float* __restrict__ temp,
                                                    ushort* __restrict__ Sca)
{
    const int bh = blockIdx.x;
    const int hsel = bh & 3;
    const int t = threadIdx.x;
    const int i = t >> 2, q = t & 3;
    const float sT = 0.125f * temp[hsel];

    float v[16];
    #pragma unroll
    for (int jj = 0; jj < 16; ++jj) v[jj] = 0.f;
    #pragma unroll
    for (int cc = 0; cc < 8; ++cc) {
        const float* p = &part[((size_t)bh * 8 + cc) * 4096 + i * 64 + q * 16];
        #pragma unroll
        for (int j4 = 0; j4 < 4; ++j4) {
            float4 f = *(const float4*)&p[j4 * 4];
            v[j4 * 4 + 0] += f.x; v[j4 * 4 + 1] += f.y;
            v[j4 * 4 + 2] += f.z; v[j4 * 4 + 3] += f.w;
        }
    }
    float m = -1e30f;
    #pragma unroll
    for (int jj = 0; jj < 16; ++jj) { v[jj] *= sT; m = fmaxf(m, v[jj]); }
    m = fmaxf(m, __shfl_xor(m, 1, 4));
    m = fmaxf(m, __shfl_xor(m, 2, 4));
    float sum = 0.f;
    #pragma unroll
    for (int jj = 0; jj < 16; ++jj) { v[jj] = __expf(v[jj] - m); sum += v[jj]; }
    sum += __shfl_xor(sum, 1, 4);
    sum += __shfl_xor(sum, 2, 4);
    const float inv = 1.0f / sum;
    ushort* dst = &Sca[((size_t)bh << 12) + i * 64 + q * 16];
    #pragma unroll
    for (int j4 = 0; j4 < 4; ++j4) {
        ushort4 r;
        r.x = f2bf(v[j4 * 4 + 0] * inv); r.y = f2bf(v[j4 * 4 + 1] * inv);
        r.z = f2bf(v[j4 * 4 + 2] * inv); r.w = f2bf(v[j4 * 4 + 3] * inv);
        *(ushort4*)&dst[j4 * 4] = r;
    }
}

// ---------------------------------------------------------------------------
// Channel stage 3 via MFMA — unchanged from round 3 (verified).
// ---------------------------------------------------------------------------
__global__ __launch_bounds__(256) void chan_pv_mfma(const ushort* __restrict__ Sca,
                                                    const ushort* __restrict__ Pvc,
                                                    float* __restrict__ out)
{
    const int nc = blockIdx.x, hh = blockIdx.y, b = blockIdx.z;
    const int t = threadIdx.x;
    const int w = t >> 6, l = t & 63, c = l & 15, g = l >> 4;

    const ushort* S = Sca + ((size_t)(b * 4 + hh) << 12);
    const ushort* V = Pvc + (size_t)b * PROJ_EL + (size_t)hh * HEAD_EL;
    const int n0w = nc * 256 + w * 64;

    f32x4 acc[4][4] = {};
    #pragma unroll
    for (int ks = 0; ks < 2; ++ks) {
        short8_t af[4], bfr[4];
        #pragma unroll
        for (int rt = 0; rt < 4; ++rt)
            af[rt] = *(const short8_t*)&S[(size_t)(rt * 16 + c) * 64 + ks * 32 + 8 * g];
        #pragma unroll
        for (int ct = 0; ct < 4; ++ct)
            bfr[ct] = *(const short8_t*)&V[(size_t)(n0w + ct * 16 + c) * 64 + ks * 32 + 8 * g];
        #pragma unroll
        for (int rt = 0; rt < 4; ++rt)
            #pragma unroll
            for (int ct = 0; ct < 4; ++ct)
                acc[rt][ct] = __builtin_amdgcn_mfma_f32_16x16x32_bf16(
                    af[rt], bfr[ct], acc[rt][ct], 0, 0, 0);
    }

    float* ob = out + (size_t)b * (Nn * 320);
    #pragma unroll
    for (int rt = 0; rt < 4; ++rt)
        #pragma unroll
        for (int ct = 0; ct < 4; ++ct)
            #pragma unroll
            for (int r = 0; r < 4; ++r) {
                int i = rt * 16 + 4 * g + r;
                int nn = n0w + ct * 16 + c;
                int rem = hh * 131072 + i * 2048 + nn;
                ob[(rem >> 8) * 320 + (rem & 255)] = acc[rt][ct][r];
            }
}

// ---------------------------------------------------------------------------
// Spatial attention, round 14. 256 blocks (XCD decode = r13) x 512 thr =
// 8 waves = 4 q-groups x 2 KV-halves. Wave owns 32 q-rows (2 subtiles, shared
// K frags) and 16 KV tiles. Single barrier/iter double-buffer per half
// (r13 pattern). KV-halves combine additively via f32 LDS (r7 pattern).
// ---------------------------------------------------------------------------
__global__ __launch_bounds__(512, 2) void spatial_attn10(
    const ushort* __restrict__ Pqs, const ushort* __restrict__ Pks,
    const ushort* __restrict__ PvsT, const float* __restrict__ temp2,
    float* __restrict__ out)
{
    const int i0 = blockIdx.x;
    const int xcd = i0 & 7, j = i0 >> 3;       // j in [0,32)
    const int hsel = xcd + 8 * (j & 1);        // 0..15 = b*4+hh
    const int qb = j >> 1;                     // 0..15
    const int b = hsel >> 2, hh = hsel & 3;

    const int t = threadIdx.x, w = t >> 6, l = t & 63;
    const int c = l & 15, g = l >> 4;
    const int qg = w >> 1, kh = w & 1;         // 4 q-groups x 2 KV halves

    __shared__ ushort Kbuf[2][2][64][72];      // [half][dbuf] 36.9 KB
    __shared__ ushort Vbuf[2][2][16][72];      //  9.2 KB
    __shared__ ushort P_lds[8][2][16][72];     // [wave][subtile] 36.9 KB
    __shared__ float  O_red[8][2][16][16];     // 16.4 KB
    __shared__ float  L_red[8][2][16];         //  1.0 KB

    const ushort* Qh = Pqs + (size_t)b * PROJ_EL + (size_t)hh * HEAD_EL;
    const ushort* Kh = Pks + (size_t)b * PROJ_EL + (size_t)hh * HEAD_EL;
    const ushort* Vt = PvsT + (size_t)((b * 4 + hh) * 16) * 2048;   // (16, 2048)
    const float sT2 = 0.125f * temp2[hh] * 1.44269504f;   // fold log2(e)

    const int q0 = qb * 128 + qg * 32;         // wave: rows q0..q0+31
    const ushort* qpA = Qh + (size_t)(q0 + c) * 64 + 8 * g;
    const ushort* qpB = qpA + 16 * 64;
    const short8_t qfA0 = *(const short8_t*)qpA;
    const short8_t qfA1 = *(const short8_t*)(qpA + 32);
    const short8_t qfB0 = *(const short8_t*)qpB;
    const short8_t qfB1 = *(const short8_t*)(qpB + 32);

    f32x4 oaccA = {0.f, 0.f, 0.f, 0.f}, oaccB = {0.f, 0.f, 0.f, 0.f};
    float lsumA = 0.f, lsumB = 0.f;
    ushort* PwA = &P_lds[w][0][0][0];          // row stride 72 ushorts
    ushort* PwB = &P_lds[w][1][0][0];

    // staging: 256 threads per half; thread stages 32B of K + 8B of V
    const int sh_ = t >> 8, th = t & 255;
    const int krow = th >> 2, ksub = (th & 3) * 16;
    const int vrow = th >> 4, vcol = (th & 15) * 4;

    // prologue: stage local tile 0 of half sh_ into dbuf 0
    {
        const int kb = (sh_ * 16) * 64;
        short8_t k0 = *(const short8_t*)&Kh[(size_t)(kb + krow) * 64 + ksub];
        short8_t k1 = *(const short8_t*)&Kh[(size_t)(kb + krow) * 64 + ksub + 8];
        uint2 v0 = *(const uint2*)&Vt[(size_t)vrow * 2048 + kb + vcol];
        *(short8_t*)&Kbuf[sh_][0][krow][ksub]     = k0;
        *(short8_t*)&Kbuf[sh_][0][krow][ksub + 8] = k1;
        *(uint2*)&Vbuf[sh_][0][vrow][vcol] = v0;
    }

    short8_t kreg0, kreg1; uint2 vreg;
    for (int it = 0; it < 16; ++it) {
        const int cur = it & 1;
        const int kb = (kh * 16 + it) * 64;        // compute tile (this wave)

        // issue next tile's global loads for staging half sh_
        if (it < 15) {
            const int nb = (sh_ * 16 + it + 1) * 64;
            kreg0 = *(const short8_t*)&Kh[(size_t)(nb + krow) * 64 + ksub];
            kreg1 = *(const short8_t*)&Kh[(size_t)(nb + krow) * 64 + ksub + 8];
            vreg = *(const uint2*)&Vt[(size_t)vrow * 2048 + nb + vcol];
        }
        (void)kb;

        __syncthreads();   // buf[*][cur] visible to all waves

        // QK^T for both subtiles (shared K frags), lane-local softmax
        #pragma unroll
        for (int tc = 0; tc < 4; ++tc) {
            short8_t kf0 = *(const short8_t*)&Kbuf[kh][cur][tc * 16 + c][8 * g];
            short8_t kf1 = *(const short8_t*)&Kbuf[kh][cur][tc * 16 + c][32 + 8 * g];
            f32x4 z = {0.f, 0.f, 0.f, 0.f};
            f32x4 sa = __builtin_amdgcn_mfma_f32_16x16x32_bf16(kf0, qfA0, z, 0, 0, 0);
            sa = __builtin_amdgcn_mfma_f32_16x16x32_bf16(kf1, qfA1, sa, 0, 0, 0);
            f32x4 sb2 = __builtin_amdgcn_mfma_f32_16x16x32_bf16(kf0, qfB0, z, 0, 0, 0);
            sb2 = __builtin_amdgcn_mfma_f32_16x16x32_bf16(kf1, qfB1, sb2, 0, 0, 0);

            float a0 = __builtin_amdgcn_exp2f(sa[0] * sT2);
            float a1 = __builtin_amdgcn_exp2f(sa[1] * sT2);
            float a2 = __builtin_amdgcn_exp2f(sa[2] * sT2);
            float a3 = __builtin_amdgcn_exp2f(sa[3] * sT2);
            lsumA += (a0 + a1) + (a2 + a3);
            unsigned ua, ub;
            asm("v_cvt_pk_bf16_f32 %0, %1, %2" : "=v"(ua) : "v"(a0), "v"(a1));
            asm("v_cvt_pk_bf16_f32 %0, %1, %2" : "=v"(ub) : "v"(a2), "v"(a3));
            *(unsigned*)&PwA[(size_t)c * 72 + tc * 16 + 4 * g]     = ua;
            *(unsigned*)&PwA[(size_t)c * 72 + tc * 16 + 4 * g + 2] = ub;

            float b0 = __builtin_amdgcn_exp2f(sb2[0] * sT2);
            float b1 = __builtin_amdgcn_exp2f(sb2[1] * sT2);
            float b2 = __builtin_amdgcn_exp2f(sb2[2] * sT2);
            float b3 = __builtin_amdgcn_exp2f(sb2[3] * sT2);
            lsumB += (b0 + b1) + (b2 + b3);
            unsigned vb0, vb1;
            asm("v_cvt_pk_bf16_f32 %0, %1, %2" : "=v"(vb0) : "v"(b0), "v"(b1));
            asm("v_cvt_pk_bf16_f32 %0, %1, %2" : "=v"(vb1) : "v"(b2), "v"(b3));
            *(unsigned*)&PwB[(size_t)c * 72 + tc * 16 + 4 * g]     = vb0;
            *(unsigned*)&PwB[(size_t)c * 72 + tc * 16 + 4 * g + 2] = vb1;
        }
        __builtin_amdgcn_sched_barrier(0);
        // PV for both subtiles (V frags shared)
        #pragma unroll
        for (int ks = 0; ks < 2; ++ks) {
            short8_t vf = *(const short8_t*)&Vbuf[kh][cur][c][ks * 32 + 8 * g];
            short8_t pfA = *(const short8_t*)&PwA[(size_t)c * 72 + ks * 32 + 8 * g];
            oaccA = __builtin_amdgcn_mfma_f32_16x16x32_bf16(vf, pfA, oaccA, 0, 0, 0);
            short8_t pfB = *(const short8_t*)&PwB[(size_t)c * 72 + ks * 32 + 8 * g];
            oaccB = __builtin_amdgcn_mfma_f32_16x16x32_bf16(vf, pfB, oaccB, 0, 0, 0);
        }

        // write next tile into the other dbuf (nobody reads it this iter)
        if (it < 15) {
            *(short8_t*)&Kbuf[sh_][cur ^ 1][krow][ksub]     = kreg0;
            *(short8_t*)&Kbuf[sh_][cur ^ 1][krow][ksub + 8] = kreg1;
            *(uint2*)&Vbuf[sh_][cur ^ 1][vrow][vcol] = vreg;
        }
    }

    // per-wave full row-sums for q = c (across the 4 lane-groups)
    lsumA += __shfl_xor(lsumA, 16);
    lsumA += __shfl_xor(lsumA, 32);
    lsumB += __shfl_xor(lsumB, 16);
    lsumB += __shfl_xor(lsumB, 32);

    // stash partials; combine the 2 KV halves (waves qg*2 and qg*2+1)
    *(float4*)&O_red[w][0][c][4 * g] = make_float4(oaccA[0], oaccA[1], oaccA[2], oaccA[3]);
    *(float4*)&O_red[w][1][c][4 * g] = make_float4(oaccB[0], oaccB[1], oaccB[2], oaccB[3]);
    if (g == 0) { L_red[w][0][c] = lsumA; L_red[w][1][c] = lsumB; }
    __syncthreads();

    if (kh == 0) {
        #pragma unroll
        for (int ss = 0; ss < 2; ++ss) {
            float4 o0 = *(const float4*)&O_red[w][ss][c][4 * g];
            float4 o1 = *(const float4*)&O_red[w + 1][ss][c][4 * g];
            float ltot = L_red[w][ss][c] + L_red[w + 1][ss][c];
            const float inv = 1.0f / ltot;
            const int nn = q0 + ss * 16 + c;
            const int n = hh * 512 + (nn >> 2);
            const int cc = 256 + ((nn & 3) << 4) + 4 * g;
            float4 o4 = make_float4((o0.x + o1.x) * inv, (o0.y + o1.y) * inv,
                                    (o0.z + o1.z) * inv, (o0.w + o1.w) * inv);
            *(float4*)&out[((size_t)b * Nn + n) * 320 + cc] = o4;
        }
    }
}

// ---------------------------------------------------------------------------
extern "C" void kernel_launch(void* const* d_in, const int* in_sizes, int n_in,
                              void* d_out, int out_size, void* d_ws, size_t ws_size,
                              hipStream_t stream)
{
    const float* s     = (const float*)d_in[0];
    const float* h     = (const float*)d_in[1];
    const float* sh    = (const float*)d_in[2];
    const float* temp  = (const float*)d_in[3];
    const float* temp2 = (const float*)d_in[4];
    const float* Wq_c  = (const float*)d_in[5];
    const float* Wq_s  = (const float*)d_in[6];
    const float* Wk_c  = (const float*)d_in[7];
    const float* Wv_c  = (const float*)d_in[8];
    const float* Wk_s  = (const float*)d_in[9];
    const float* Wv_s  = (const float*)d_in[10];
    float* out = (float*)d_out;
    float* ws = (float*)d_ws;

    ushort* sb    = (ushort*)(ws + OFF_SB);
    ushort* shb   = (ushort*)(ws + OFF_SHB);
    ushort* hb    = (ushort*)(ws + OFF_HB);
    ushort* wqcb  = (ushort*)(ws + OFF_WQC);
    ushort* wcatb = (ushort*)(ws + OFF_WCAT);
    ushort* wvsb  = (ushort*)(ws + OFF_WVS);
    ushort* Pqc   = (ushort*)(ws + OFF_PQC);
    ushort* Pqs   = (ushort*)(ws + OFF_PQS);
    ushort* Pkc   = (ushort*)(ws + OFF_PKC);
    ushort* Pvc   = (ushort*)(ws + OFF_PVC);
    ushort* Pks   = (ushort*)(ws + OFF_PKS);
    ushort* PvsT  = (ushort*)(ws + OFF_PVST);
    float*  part  = ws + OFF_PART;
    ushort* Sca   = (ushort*)(ws + OFF_SCA);

    const dim3 blk(256);

    // 1) f32 -> bf16 conversions
    convert_all<<<dim3((SEG8 / 8 + 255) / 256), blk, 0, stream>>>(
        s, sh, h, Wq_c, Wq_s, Wk_c, Wv_c, Wk_s, Wv_s,
        sb, shb, hb, wqcb, wcatb, wvsb);

    // 2) projections
    mfma_gemm<<<dim3(8, 64), blk, 0, stream>>>(shb, wcatb, Pqs, Pkc, Pvc, Pks, 256);
    mfma_gemm<<<dim3(2, 64), blk, 0, stream>>>(sb, wqcb, Pqc, Pqc, Pqc, Pqc, 256);
    mfma_gemm_vs<<<dim3(32), blk, 0, stream>>>(wvsb, hb, PvsT);

    // 3) channel branch
    chan_qk_partial<<<dim3(8, 4, 4), blk, 0, stream>>>(Pqc, Pkc, part);
    chan_softmax<<<dim3(16), blk, 0, stream>>>(part, temp, Sca);
    chan_pv_mfma<<<dim3(8, 4, 4), blk, 0, stream>>>(Sca, Pvc, out);

    // 4) spatial branch (2 subtiles/wave sharing K frags, split-KV x2)
    spatial_attn10<<<dim3(256), dim3(512), 0, stream>>>(Pqs, Pks, PvsT, temp2, out);
}

// Round 15
// 70.908 us; speedup vs baseline: 1.3775x; 1.0741x over previous
//
#include <hip/hip_runtime.h>
#include <math.h>

// ---------------------------------------------------------------------------
// WCSA round 15 = round 14 (passing, 76.2us) + launch-level fusion ONLY
// (all math bit-identical):
//  (1) proj_all: the 3 projection GEMMs in one 672-block dispatch
//      (512 sh-GEMM + 128 s-GEMM + 32 vs-GEMM, block-routed).
//  (2) spatial_pv: chan_pv folded into the spatial dispatch as blocks 0..63
//      (zero-LDS, no barriers -> trivial wave-task decode).
// Dispatches: 8 -> 5.
// ---------------------------------------------------------------------------

constexpr int Bb = 4, Nn = 2048, Hh = 4;
constexpr int PROJ_EL = Nn * 256;
constexpr int HEAD_EL = Nn * 64;

typedef __attribute__((ext_vector_type(8))) short short8_t;   // 8 bf16
typedef __attribute__((ext_vector_type(4))) float f32x4;

__device__ __forceinline__ ushort f2bf(float x) {
    union { float f; unsigned u; } v; v.f = x;
    unsigned r = v.u + 0x7fffu + ((v.u >> 16) & 1u);   // RNE
    return (ushort)(r >> 16);
}
__device__ __forceinline__ float bf2f(ushort x) {
    union { unsigned u; float f; } v; v.u = ((unsigned)x) << 16;
    return v.f;
}

// ---------------- workspace layout (float granularity) ---------------------
constexpr size_t OFF_SB    = 0;
constexpr size_t OFF_SHB   = OFF_SB   + 1024 * 1024;
constexpr size_t OFF_HB    = OFF_SHB  + 1024 * 1024;
constexpr size_t OFF_WQC   = OFF_HB   + 256 * 1024;
constexpr size_t OFF_WCAT  = OFF_WQC  + 32 * 1024;
constexpr size_t OFF_PQC   = OFF_WCAT + 128 * 1024;
constexpr size_t OFF_PQS   = OFF_PQC  + 1024 * 1024;
constexpr size_t OFF_PKC   = OFF_PQS  + 1024 * 1024;
constexpr size_t OFF_PVC   = OFF_PKC  + 1024 * 1024;
constexpr size_t OFF_PKS   = OFF_PVC  + 1024 * 1024;
constexpr size_t OFF_PVST  = OFF_PKS  + 1024 * 1024;
constexpr size_t OFF_PART  = OFF_PVST + 256 * 1024;
constexpr size_t OFF_SCA   = OFF_PART + 512 * 1024;
constexpr size_t OFF_WVS   = OFF_SCA  + 32 * 1024;

// ---------------------------------------------------------------------------
// Convert all needed f32 arrays to bf16 in one pass (unchanged, verified).
// ---------------------------------------------------------------------------
constexpr unsigned SEG0 = 2097152;
constexpr unsigned SEG1 = SEG0 + 2097152;
constexpr unsigned SEG2 = SEG1 + 524288;
constexpr unsigned SEG3 = SEG2 + 65536;
constexpr unsigned SEG4 = SEG3 + 65536;
constexpr unsigned SEG5 = SEG4 + 65536;
constexpr unsigned SEG6 = SEG5 + 65536;
constexpr unsigned SEG7 = SEG6 + 65536;
constexpr unsigned SEG8 = SEG7 + 4096;

__global__ __launch_bounds__(256) void convert_all(
    const float* __restrict__ s, const float* __restrict__ sh,
    const float* __restrict__ h, const float* __restrict__ wqc,
    const float* __restrict__ wqs, const float* __restrict__ wkc,
    const float* __restrict__ wvc, const float* __restrict__ wks,
    const float* __restrict__ wvs,
    ushort* __restrict__ sb, ushort* __restrict__ shb, ushort* __restrict__ hb,
    ushort* __restrict__ wqcb, ushort* __restrict__ wcatb, ushort* __restrict__ wvsb)
{
    unsigned e = (blockIdx.x * 256u + threadIdx.x) * 8u;
    if (e >= SEG8) return;
    const float* src; ushort* dst; unsigned off;
    if      (e < SEG0) { src = s;   dst = sb;             off = e; }
    else if (e < SEG1) { src = sh;  dst = shb;            off = e - SEG0; }
    else if (e < SEG2) { src = h;   dst = hb;             off = e - SEG1; }
    else if (e < SEG3) { src = wqc; dst = wqcb;           off = e - SEG2; }
    else if (e < SEG4) { src = wqs; dst = wcatb;          off = e - SEG3; }
    else if (e < SEG5) { src = wkc; dst = wcatb + 65536;  off = e - SEG4; }
    else if (e < SEG6) { src = wvc; dst = wcatb + 131072; off = e - SEG5; }
    else if (e < SEG7) { src = wks; dst = wcatb + 196608; off = e - SEG6; }
    else               { src = wvs; dst = wvsb;           off = e - SEG7; }
    float4 f0 = *(const float4*)&src[off];
    float4 f1 = *(const float4*)&src[off + 4];
    short8_t o;
    o[0] = f2bf(f0.x); o[1] = f2bf(f0.y); o[2] = f2bf(f0.z); o[3] = f2bf(f0.w);
    o[4] = f2bf(f1.x); o[5] = f2bf(f1.y); o[6] = f2bf(f1.z); o[7] = f2bf(f1.w);
    *(short8_t*)&dst[off] = o;
}

// ---------------------------------------------------------------------------
// GEMM tile body (r11 verbatim as device function): padded-LDS reg staging.
// ---------------------------------------------------------------------------
__device__ __forceinline__ void gemm_tile_body(
    const ushort* __restrict__ X, const ushort* __restrict__ W,
    ushort* __restrict__ d0, ushort* __restrict__ d1,
    ushort* __restrict__ d2, ushort* __restrict__ d3, int K,
    int m0, int n0, ushort (*Xs)[72], ushort (*Ws)[72])
{
    const int t = threadIdx.x;
    const int w = t >> 6, l = t & 63, c = l & 15, g = l >> 4;
    const int wr = w >> 1, wc = w & 1;

    f32x4 acc[4][4] = {};

    const int srow = t >> 2, scs = (t & 3) * 16;
    for (int k0 = 0; k0 < K; k0 += 64) {
        __syncthreads();
        #pragma unroll
        for (int p = 0; p < 2; ++p) {
            const ushort* xs = &X[(size_t)(m0 + p * 64 + srow) * K + k0 + scs];
            *(short8_t*)&Xs[p * 64 + srow][scs]     = *(const short8_t*)xs;
            *(short8_t*)&Xs[p * 64 + srow][scs + 8] = *(const short8_t*)(xs + 8);
            const ushort* wsp = &W[(size_t)(n0 + p * 64 + srow) * K + k0 + scs];
            *(short8_t*)&Ws[p * 64 + srow][scs]     = *(const short8_t*)wsp;
            *(short8_t*)&Ws[p * 64 + srow][scs + 8] = *(const short8_t*)(wsp + 8);
        }
        __syncthreads();
        #pragma unroll
        for (int ks = 0; ks < 2; ++ks) {
            short8_t af[4], bf[4];
            #pragma unroll
            for (int rt = 0; rt < 4; ++rt)
                af[rt] = *(const short8_t*)&Xs[wr * 64 + rt * 16 + c][ks * 32 + 8 * g];
            #pragma unroll
            for (int ct = 0; ct < 4; ++ct)
                bf[ct] = *(const short8_t*)&Ws[wc * 64 + ct * 16 + c][ks * 32 + 8 * g];
            #pragma unroll
            for (int rt = 0; rt < 4; ++rt)
                #pragma unroll
                for (int ct = 0; ct < 4; ++ct)
                    acc[rt][ct] = __builtin_amdgcn_mfma_f32_16x16x32_bf16(
                        af[rt], bf[ct], acc[rt][ct], 0, 0, 0);
        }
    }

    const int seg = n0 >> 8;
    ushort* dst = seg == 0 ? d0 : seg == 1 ? d1 : seg == 2 ? d2 : d3;
    const int colbase = (n0 & 255) + wc * 64;
    #pragma unroll
    for (int rt = 0; rt < 4; ++rt)
        #pragma unroll
        for (int ct = 0; ct < 4; ++ct)
            #pragma unroll
            for (int r = 0; r < 4; ++r) {
                int mrow = m0 + wr * 64 + rt * 16 + 4 * g + r;
                int col = colbase + ct * 16 + c;
                dst[(size_t)mrow * 256 + col] = f2bf(acc[rt][ct][r]);
            }
}

// ---------------------------------------------------------------------------
// v_s^T tile body (r6 verbatim as device function).
// ---------------------------------------------------------------------------
__device__ __forceinline__ void vs_tile_body(
    const ushort* __restrict__ Wvs, const ushort* __restrict__ Hb,
    ushort* __restrict__ Cvt, int vbid)
{
    const int t = threadIdx.x;
    const int w = t >> 6, l = t & 63, c = l & 15, g = l >> 4;
    const int n0 = vbid * 256 + w * 64;

    f32x4 acc[4][4] = {};
    #pragma unroll
    for (int ks = 0; ks < 2; ++ks) {
        short8_t af[4], bfr[4];
        #pragma unroll
        for (int rt = 0; rt < 4; ++rt)
            af[rt] = *(const short8_t*)&Wvs[(size_t)(rt * 16 + c) * 64 + ks * 32 + 8 * g];
        #pragma unroll
        for (int ct = 0; ct < 4; ++ct)
            bfr[ct] = *(const short8_t*)&Hb[(size_t)(n0 + ct * 16 + c) * 64 + ks * 32 + 8 * g];
        #pragma unroll
        for (int rt = 0; rt < 4; ++rt)
            #pragma unroll
            for (int ct = 0; ct < 4; ++ct)
                acc[rt][ct] = __builtin_amdgcn_mfma_f32_16x16x32_bf16(
                    af[rt], bfr[ct], acc[rt][ct], 0, 0, 0);
    }
    #pragma unroll
    for (int rt = 0; rt < 4; ++rt)
        #pragma unroll
        for (int ct = 0; ct < 4; ++ct)
            #pragma unroll
            for (int r = 0; r < 4; ++r) {
                int cc = rt * 16 + 4 * g + r;
                int m  = n0 + ct * 16 + c;
                int b  = m >> 11, n = m & 2047;
                int L  = n * 64 + cc;
                int hh = L >> 15;
                int k  = (L & 32767) >> 4;
                int d  = L & 15;
                Cvt[(size_t)((b * 4 + hh) * 16 + d) * 2048 + k] = f2bf(acc[rt][ct][r]);
            }
}

// ---------------------------------------------------------------------------
// Fused projection dispatch: 672 blocks x 256 thr.
//  bid <512: sh @ Wcat^T (bx=bid&7, by=bid>>3)
//  bid <640: s @ Wq_c^T  (bx=(bid-512)&1, by=(bid-512)>>1)
//  else    : Wv_s @ h^T v_s^T producer (vbid = bid-640)
// ---------------------------------------------------------------------------
__global__ __launch_bounds__(256) void proj_all(
    const ushort* __restrict__ shb, const ushort* __restrict__ wcatb,
    ushort* __restrict__ Pqs, ushort* __restrict__ Pkc,
    ushort* __restrict__ Pvc, ushort* __restrict__ Pks,
    const ushort* __restrict__ sb, const ushort* __restrict__ wqcb,
    ushort* __restrict__ Pqc,
    const ushort* __restrict__ wvsb, const ushort* __restrict__ hb,
    ushort* __restrict__ PvsT)
{
    __shared__ ushort Xs[128][72];
    __shared__ ushort Ws[128][72];
    const int bid = blockIdx.x;
    if (bid < 512) {
        gemm_tile_body(shb, wcatb, Pqs, Pkc, Pvc, Pks, 256,
                       (bid >> 3) * 128, (bid & 7) * 128, Xs, Ws);
    } else if (bid < 640) {
        const int r = bid - 512;
        gemm_tile_body(sb, wqcb, Pqc, Pqc, Pqc, Pqc, 256,
                       (r >> 1) * 128, (r & 1) * 128, Xs, Ws);
    } else {
        vs_tile_body(wvsb, hb, PvsT, bid - 640);
    }
}

// ---------------------------------------------------------------------------
// Channel stage 1 (unchanged, verified).
// ---------------------------------------------------------------------------
__global__ __launch_bounds__(256) void chan_qk_partial(const ushort* __restrict__ Pqc,
                                                       const ushort* __restrict__ Pkc,
                                                       float* __restrict__ part)
{
    const int ch = blockIdx.x, hh = blockIdx.y, b = blockIdx.z;
    const ushort* Q = Pqc + (size_t)b * PROJ_EL + (size_t)hh * HEAD_EL;
    const ushort* Kk = Pkc + (size_t)b * PROJ_EL + (size_t)hh * HEAD_EL;
    __shared__ float Qs[64][68], Ks[64][68];
    const int t = threadIdx.x, ty = t >> 4, tx = t & 15;

    float acc[4][4] = {};
    for (int sub = 0; sub < 4; ++sub) {
        const int r0 = ch * 256 + sub * 64;
        __syncthreads();
        #pragma unroll
        for (int q = t; q < 512; q += 256) {
            int row = q >> 3, c8 = (q & 7) * 8;
            short8_t qv = *(const short8_t*)&Q[(size_t)(r0 + row) * 64 + c8];
            short8_t kv = *(const short8_t*)&Kk[(size_t)(r0 + row) * 64 + c8];
            #pragma unroll
            for (int j = 0; j < 8; ++j) {
                Qs[row][c8 + j] = bf2f((ushort)qv[j]);
                Ks[row][c8 + j] = bf2f((ushort)kv[j]);
            }
        }
        __syncthreads();
        #pragma unroll 8
        for (int nn = 0; nn < 64; ++nn) {
            float4 q4 = *(const float4*)&Qs[nn][ty * 4];
            float4 k4 = *(const float4*)&Ks[nn][tx * 4];
            float qa[4] = {q4.x, q4.y, q4.z, q4.w};
            float ka[4] = {k4.x, k4.y, k4.z, k4.w};
            #pragma unroll
            for (int ii = 0; ii < 4; ++ii)
                #pragma unroll
                for (int jj = 0; jj < 4; ++jj)
                    acc[ii][jj] += qa[ii] * ka[jj];
        }
    }
    float* P = part + (((size_t)(b * 4 + hh) * 8 + ch) << 12);
    #pragma unroll
    for (int ii = 0; ii < 4; ++ii)
        *(float4*)&P[(ty * 4 + ii) * 64 + tx * 4] =
            make_float4(acc[ii][0], acc[ii][1], acc[ii][2], acc[ii][3]);
}

// ---------------------------------------------------------------------------
// Channel stage 2 (r13 vectorized, verified).
// ---------------------------------------------------------------------------
__global__ __launch_bounds__(256) void chan_softmax(const float* __restrict__ part,
                                                    const float* __restrict__ temp,
                                                    ushort* __restrict__ Sca)
{
    const int bh = blockIdx.x;
    const int hsel = bh & 3;
    const int t = threadIdx.x;
    const int i = t >> 2, q = t & 3;
    const float sT = 0.125f * temp[hsel];

    float v[16];
    #pragma unroll
    for (int jj = 0; jj < 16; ++jj) v[jj] = 0.f;
    #pragma unroll
    for (int cc = 0; cc < 8; ++cc) {
        const float* p = &part[((size_t)bh * 8 + cc) * 4096 + i * 64 + q * 16];
        #pragma unroll
        for (int j4 = 0; j4 < 4; ++j4) {
            float4 f = *(const float4*)&p[j4 * 4];
            v[j4 * 4 + 0] += f.x; v[j4 * 4 + 1] += f.y;
            v[j4 * 4 + 2] += f.z; v[j4 * 4 + 3] += f.w;
        }
    }
    float m = -1e30f;
    #pragma unroll
    for (int jj = 0; jj < 16; ++jj) { v[jj] *= sT; m = fmaxf(m, v[jj]); }
    m = fmaxf(m, __shfl_xor(m, 1, 4));
    m = fmaxf(m, __shfl_xor(m, 2, 4));
    float sum = 0.f;
    #pragma unroll
    for (int jj = 0; jj < 16; ++jj) { v[jj] = __expf(v[jj] - m); sum += v[jj]; }
    sum += __shfl_xor(sum, 1, 4);
    sum += __shfl_xor(sum, 2, 4);
    const float inv = 1.0f / sum;
    ushort* dst = &Sca[((size_t)bh << 12) + i * 64 + q * 16];
    #pragma unroll
    for (int j4 = 0; j4 < 4; ++j4) {
        ushort4 r;
        r.x = f2bf(v[j4 * 4 + 0] * inv); r.y = f2bf(v[j4 * 4 + 1] * inv);
        r.z = f2bf(v[j4 * 4 + 2] * inv); r.w = f2bf(v[j4 * 4 + 3] * inv);
        *(ushort4*)&dst[j4 * 4] = r;
    }
}

// ---------------------------------------------------------------------------
// chan_pv wave-task body (r3 verbatim; zero LDS, no barriers).
// ---------------------------------------------------------------------------
__device__ __forceinline__ void chan_pv_body(
    const ushort* __restrict__ Sca, const ushort* __restrict__ Pvc,
    float* __restrict__ out, int b, int hh, int nc, int wv, int l)
{
    const int c = l & 15, g = l >> 4;
    const ushort* S = Sca + ((size_t)(b * 4 + hh) << 12);
    const ushort* V = Pvc + (size_t)b * PROJ_EL + (size_t)hh * HEAD_EL;
    const int n0w = nc * 256 + wv * 64;

    f32x4 acc[4][4] = {};
    #pragma unroll
    for (int ks = 0; ks < 2; ++ks) {
        short8_t af[4], bfr[4];
        #pragma unroll
        for (int rt = 0; rt < 4; ++rt)
            af[rt] = *(const short8_t*)&S[(size_t)(rt * 16 + c) * 64 + ks * 32 + 8 * g];
        #pragma unroll
        for (int ct = 0; ct < 4; ++ct)
            bfr[ct] = *(const short8_t*)&V[(size_t)(n0w + ct * 16 + c) * 64 + ks * 32 + 8 * g];
        #pragma unroll
        for (int rt = 0; rt < 4; ++rt)
            #pragma unroll
            for (int ct = 0; ct < 4; ++ct)
                acc[rt][ct] = __builtin_amdgcn_mfma_f32_16x16x32_bf16(
                    af[rt], bfr[ct], acc[rt][ct], 0, 0, 0);
    }

    float* ob = out + (size_t)b * (Nn * 320);
    #pragma unroll
    for (int rt = 0; rt < 4; ++rt)
        #pragma unroll
        for (int ct = 0; ct < 4; ++ct)
            #pragma unroll
            for (int r = 0; r < 4; ++r) {
                int i = rt * 16 + 4 * g + r;
                int nn = n0w + ct * 16 + c;
                int rem = hh * 131072 + i * 2048 + nn;
                ob[(rem >> 8) * 320 + (rem & 255)] = acc[rt][ct][r];
            }
}

// ---------------------------------------------------------------------------
// Fused spatial + chan_pv dispatch. Blocks 0..63: chan_pv (8 wave-tasks
// each, decode (b,hh,nc,wv)). Blocks 64..319: spatial (r14 verbatim with
// i0 = blockIdx.x - 64).
// ---------------------------------------------------------------------------
__global__ __launch_bounds__(512, 2) void spatial_pv(
    const ushort* __restrict__ Pqs, const ushort* __restrict__ Pks,
    const ushort* __restrict__ PvsT, const float* __restrict__ temp2,
    const ushort* __restrict__ Sca, const ushort* __restrict__ Pvc,
    float* __restrict__ out)
{
    if (blockIdx.x < 64) {
        const int task = blockIdx.x * 8 + (threadIdx.x >> 6);
        const int b2 = task >> 7, rem = task & 127;
        const int hh2 = rem >> 5, rem2 = rem & 31;
        const int nc = rem2 >> 2, wv = rem2 & 3;
        chan_pv_body(Sca, Pvc, out, b2, hh2, nc, wv, threadIdx.x & 63);
        return;
    }

    const int i0 = blockIdx.x - 64;
    const int xcd = i0 & 7, j = i0 >> 3;
    const int hsel = xcd + 8 * (j & 1);
    const int qb = j >> 1;
    const int b = hsel >> 2, hh = hsel & 3;

    const int t = threadIdx.x, w = t >> 6, l = t & 63;
    const int c = l & 15, g = l >> 4;
    const int qg = w >> 1, kh = w & 1;

    __shared__ ushort Kbuf[2][2][64][72];
    __shared__ ushort Vbuf[2][2][16][72];
    __shared__ ushort P_lds[8][2][16][72];
    __shared__ float  O_red[8][2][16][16];
    __shared__ float  L_red[8][2][16];

    const ushort* Qh = Pqs + (size_t)b * PROJ_EL + (size_t)hh * HEAD_EL;
    const ushort* Kh = Pks + (size_t)b * PROJ_EL + (size_t)hh * HEAD_EL;
    const ushort* Vt = PvsT + (size_t)((b * 4 + hh) * 16) * 2048;
    const float sT2 = 0.125f * temp2[hh] * 1.44269504f;

    const int q0 = qb * 128 + qg * 32;
    const ushort* qpA = Qh + (size_t)(q0 + c) * 64 + 8 * g;
    const ushort* qpB = qpA + 16 * 64;
    const short8_t qfA0 = *(const short8_t*)qpA;
    const short8_t qfA1 = *(const short8_t*)(qpA + 32);
    const short8_t qfB0 = *(const short8_t*)qpB;
    const short8_t qfB1 = *(const short8_t*)(qpB + 32);

    f32x4 oaccA = {0.f, 0.f, 0.f, 0.f}, oaccB = {0.f, 0.f, 0.f, 0.f};
    float lsumA = 0.f, lsumB = 0.f;
    ushort* PwA = &P_lds[w][0][0][0];
    ushort* PwB = &P_lds[w][1][0][0];

    const int sh_ = t >> 8, th = t & 255;
    const int krow = th >> 2, ksub = (th & 3) * 16;
    const int vrow = th >> 4, vcol = (th & 15) * 4;

    {
        const int kb = (sh_ * 16) * 64;
        short8_t k0 = *(const short8_t*)&Kh[(size_t)(kb + krow) * 64 + ksub];
        short8_t k1 = *(const short8_t*)&Kh[(size_t)(kb + krow) * 64 + ksub + 8];
        uint2 v0 = *(const uint2*)&Vt[(size_t)vrow * 2048 + kb + vcol];
        *(short8_t*)&Kbuf[sh_][0][krow][ksub]     = k0;
        *(short8_t*)&Kbuf[sh_][0][krow][ksub + 8] = k1;
        *(uint2*)&Vbuf[sh_][0][vrow][vcol] = v0;
    }

    short8_t kreg0, kreg1; uint2 vreg;
    for (int it = 0; it < 16; ++it) {
        const int cur = it & 1;

        if (it < 15) {
            const int nb = (sh_ * 16 + it + 1) * 64;
            kreg0 = *(const short8_t*)&Kh[(size_t)(nb + krow) * 64 + ksub];
            kreg1 = *(const short8_t*)&Kh[(size_t)(nb + krow) * 64 + ksub + 8];
            vreg = *(const uint2*)&Vt[(size_t)vrow * 2048 + nb + vcol];
        }

        __syncthreads();

        #pragma unroll
        for (int tc = 0; tc < 4; ++tc) {
            short8_t kf0 = *(const short8_t*)&Kbuf[kh][cur][tc * 16 + c][8 * g];
            short8_t kf1 = *(const short8_t*)&Kbuf[kh][cur][tc * 16 + c][32 + 8 * g];
            f32x4 z = {0.f, 0.f, 0.f, 0.f};
            f32x4 sa = __builtin_amdgcn_mfma_f32_16x16x32_bf16(kf0, qfA0, z, 0, 0, 0);
            sa = __builtin_amdgcn_mfma_f32_16x16x32_bf16(kf1, qfA1, sa, 0, 0, 0);
            f32x4 sb2 = __builtin_amdgcn_mfma_f32_16x16x32_bf16(kf0, qfB0, z, 0, 0, 0);
            sb2 = __builtin_amdgcn_mfma_f32_16x16x32_bf16(kf1, qfB1, sb2, 0, 0, 0);

            float a0 = __builtin_amdgcn_exp2f(sa[0] * sT2);
            float a1 = __builtin_amdgcn_exp2f(sa[1] * sT2);
            float a2 = __builtin_amdgcn_exp2f(sa[2] * sT2);
            float a3 = __builtin_amdgcn_exp2f(sa[3] * sT2);
            lsumA += (a0 + a1) + (a2 + a3);
            unsigned ua, ub;
            asm("v_cvt_pk_bf16_f32 %0, %1, %2" : "=v"(ua) : "v"(a0), "v"(a1));
            asm("v_cvt_pk_bf16_f32 %0, %1, %2" : "=v"(ub) : "v"(a2), "v"(a3));
            *(unsigned*)&PwA[(size_t)c * 72 + tc * 16 + 4 * g]     = ua;
            *(unsigned*)&PwA[(size_t)c * 72 + tc * 16 + 4 * g + 2] = ub;

            float b0 = __builtin_amdgcn_exp2f(sb2[0] * sT2);
            float b1 = __builtin_amdgcn_exp2f(sb2[1] * sT2);
            float b2 = __builtin_amdgcn_exp2f(sb2[2] * sT2);
            float b3 = __builtin_amdgcn_exp2f(sb2[3] * sT2);
            lsumB += (b0 + b1) + (b2 + b3);
            unsigned vb0, vb1;
            asm("v_cvt_pk_bf16_f32 %0, %1, %2" : "=v"(vb0) : "v"(b0), "v"(b1));
            asm("v_cvt_pk_bf16_f32 %0, %1, %2" : "=v"(vb1) : "v"(b2), "v"(b3));
            *(unsigned*)&PwB[(size_t)c * 72 + tc * 16 + 4 * g]     = vb0;
            *(unsigned*)&PwB[(size_t)c * 72 + tc * 16 + 4 * g + 2] = vb1;
        }
        __builtin_amdgcn_sched_barrier(0);
        #pragma unroll
        for (int ks = 0; ks < 2; ++ks) {
            short8_t vf = *(const short8_t*)&Vbuf[kh][cur][c][ks * 32 + 8 * g];
            short8_t pfA = *(const short8_t*)&PwA[(size_t)c * 72 + ks * 32 + 8 * g];
            oaccA = __builtin_amdgcn_mfma_f32_16x16x32_bf16(vf, pfA, oaccA, 0, 0, 0);
            short8_t pfB = *(const short8_t*)&PwB[(size_t)c * 72 + ks * 32 + 8 * g];
            oaccB = __builtin_amdgcn_mfma_f32_16x16x32_bf16(vf, pfB, oaccB, 0, 0, 0);
        }

        if (it < 15) {
            *(short8_t*)&Kbuf[sh_][cur ^ 1][krow][ksub]     = kreg0;
            *(short8_t*)&Kbuf[sh_][cur ^ 1][krow][ksub + 8] = kreg1;
            *(uint2*)&Vbuf[sh_][cur ^ 1][vrow][vcol] = vreg;
        }
    }

    lsumA += __shfl_xor(lsumA, 16);
    lsumA += __shfl_xor(lsumA, 32);
    lsumB += __shfl_xor(lsumB, 16);
    lsumB += __shfl_xor(lsumB, 32);

    *(float4*)&O_red[w][0][c][4 * g] = make_float4(oaccA[0], oaccA[1], oaccA[2], oaccA[3]);
    *(float4*)&O_red[w][1][c][4 * g] = make_float4(oaccB[0], oaccB[1], oaccB[2], oaccB[3]);
    if (g == 0) { L_red[w][0][c] = lsumA; L_red[w][1][c] = lsumB; }
    __syncthreads();

    if (kh == 0) {
        #pragma unroll
        for (int ss = 0; ss < 2; ++ss) {
            float4 o0 = *(const float4*)&O_red[w][ss][c][4 * g];
            float4 o1 = *(const float4*)&O_red[w + 1][ss][c][4 * g];
            float ltot = L_red[w][ss][c] + L_red[w + 1][ss][c];
            const float inv = 1.0f / ltot;
            const int nn = q0 + ss * 16 + c;
            const int n = hh * 512 + (nn >> 2);
            const int cc = 256 + ((nn & 3) << 4) + 4 * g;
            float4 o4 = make_float4((o0.x + o1.x) * inv, (o0.y + o1.y) * inv,
                                    (o0.z + o1.z) * inv, (o0.w + o1.w) * inv);
            *(float4*)&out[((size_t)b * Nn + n) * 320 + cc] = o4;
        }
    }
}

// ---------------------------------------------------------------------------
extern "C" void kernel_launch(void* const* d_in, const int* in_sizes, int n_in,
                              void* d_out, int out_size, void* d_ws, size_t ws_size,
                              hipStream_t stream)
{
    const float* s     = (const float*)d_in[0];
    const float* h     = (const float*)d_in[1];
    const float* sh    = (const float*)d_in[2];
    const float* temp  = (const float*)d_in[3];
    const float* temp2 = (const float*)d_in[4];
    const float* Wq_c  = (const float*)d_in[5];
    const float* Wq_s  = (const float*)d_in[6];
    const float* Wk_c  = (const float*)d_in[7];
    const float* Wv_c  = (const float*)d_in[8];
    const float* Wk_s  = (const float*)d_in[9];
    const float* Wv_s  = (const float*)d_in[10];
    float* out = (float*)d_out;
    float* ws = (float*)d_ws;

    ushort* sb    = (ushort*)(ws + OFF_SB);
    ushort* shb   = (ushort*)(ws + OFF_SHB);
    ushort* hb    = (ushort*)(ws + OFF_HB);
    ushort* wqcb  = (ushort*)(ws + OFF_WQC);
    ushort* wcatb = (ushort*)(ws + OFF_WCAT);
    ushort* wvsb  = (ushort*)(ws + OFF_WVS);
    ushort* Pqc   = (ushort*)(ws + OFF_PQC);
    ushort* Pqs   = (ushort*)(ws + OFF_PQS);
    ushort* Pkc   = (ushort*)(ws + OFF_PKC);
    ushort* Pvc   = (ushort*)(ws + OFF_PVC);
    ushort* Pks   = (ushort*)(ws + OFF_PKS);
    ushort* PvsT  = (ushort*)(ws + OFF_PVST);
    float*  part  = ws + OFF_PART;
    ushort* Sca   = (ushort*)(ws + OFF_SCA);

    const dim3 blk(256);

    // 1) f32 -> bf16 conversions
    convert_all<<<dim3((SEG8 / 8 + 255) / 256), blk, 0, stream>>>(
        s, sh, h, Wq_c, Wq_s, Wk_c, Wv_c, Wk_s, Wv_s,
        sb, shb, hb, wqcb, wcatb, wvsb);

    // 2) all projections in ONE dispatch
    proj_all<<<dim3(672), blk, 0, stream>>>(
        shb, wcatb, Pqs, Pkc, Pvc, Pks, sb, wqcb, Pqc, wvsb, hb, PvsT);

    // 3) channel branch stages 1-2
    chan_qk_partial<<<dim3(8, 4, 4), blk, 0, stream>>>(Pqc, Pkc, part);
    chan_softmax<<<dim3(16), blk, 0, stream>>>(part, temp, Sca);

    // 4) fused spatial + chan_pv
    spatial_pv<<<dim3(320), dim3(512), 0, stream>>>(
        Pqs, Pks, PvsT, temp2, Sca, Pvc, out);
}

// Round 16
// 66.767 us; speedup vs baseline: 1.4629x; 1.0620x over previous
//
#include <hip/hip_runtime.h>
#include <math.h>

// ---------------------------------------------------------------------------
// WCSA round 16 = round 15 (passing, 70.9us) + ONE change: proj_all's GEMM
// staging -> global_load_lds width-16 with rule-21-compliant XOR swizzle:
// linear [128][64] LDS dest (gload_lds requirement), inverse-swizzled per-
// lane GLOBAL source (slot ^= row&7), swizzled fragment reads (slot^(R&7)).
// Fixes r12's regression cause (linear-LDS 16-way bank conflict on reads).
// All other kernels verbatim from r15.
// ---------------------------------------------------------------------------

constexpr int Bb = 4, Nn = 2048, Hh = 4;
constexpr int PROJ_EL = Nn * 256;
constexpr int HEAD_EL = Nn * 64;

typedef __attribute__((ext_vector_type(8))) short short8_t;   // 8 bf16
typedef __attribute__((ext_vector_type(4))) float f32x4;

__device__ __forceinline__ ushort f2bf(float x) {
    union { float f; unsigned u; } v; v.f = x;
    unsigned r = v.u + 0x7fffu + ((v.u >> 16) & 1u);   // RNE
    return (ushort)(r >> 16);
}
__device__ __forceinline__ float bf2f(ushort x) {
    union { unsigned u; float f; } v; v.u = ((unsigned)x) << 16;
    return v.f;
}
// async global->LDS, 16B/lane; LDS dest = wave-uniform base + lane*16
__device__ __forceinline__ void gl_lds16(const ushort* g, ushort* l) {
    __builtin_amdgcn_global_load_lds(
        (const __attribute__((address_space(1))) void*)g,
        (__attribute__((address_space(3))) void*)l, 16, 0, 0);
}

// ---------------- workspace layout (float granularity) ---------------------
constexpr size_t OFF_SB    = 0;
constexpr size_t OFF_SHB   = OFF_SB   + 1024 * 1024;
constexpr size_t OFF_HB    = OFF_SHB  + 1024 * 1024;
constexpr size_t OFF_WQC   = OFF_HB   + 256 * 1024;
constexpr size_t OFF_WCAT  = OFF_WQC  + 32 * 1024;
constexpr size_t OFF_PQC   = OFF_WCAT + 128 * 1024;
constexpr size_t OFF_PQS   = OFF_PQC  + 1024 * 1024;
constexpr size_t OFF_PKC   = OFF_PQS  + 1024 * 1024;
constexpr size_t OFF_PVC   = OFF_PKC  + 1024 * 1024;
constexpr size_t OFF_PKS   = OFF_PVC  + 1024 * 1024;
constexpr size_t OFF_PVST  = OFF_PKS  + 1024 * 1024;
constexpr size_t OFF_PART  = OFF_PVST + 256 * 1024;
constexpr size_t OFF_SCA   = OFF_PART + 512 * 1024;
constexpr size_t OFF_WVS   = OFF_SCA  + 32 * 1024;

// ---------------------------------------------------------------------------
// Convert all needed f32 arrays to bf16 in one pass (unchanged, verified).
// ---------------------------------------------------------------------------
constexpr unsigned SEG0 = 2097152;
constexpr unsigned SEG1 = SEG0 + 2097152;
constexpr unsigned SEG2 = SEG1 + 524288;
constexpr unsigned SEG3 = SEG2 + 65536;
constexpr unsigned SEG4 = SEG3 + 65536;
constexpr unsigned SEG5 = SEG4 + 65536;
constexpr unsigned SEG6 = SEG5 + 65536;
constexpr unsigned SEG7 = SEG6 + 65536;
constexpr unsigned SEG8 = SEG7 + 4096;

__global__ __launch_bounds__(256) void convert_all(
    const float* __restrict__ s, const float* __restrict__ sh,
    const float* __restrict__ h, const float* __restrict__ wqc,
    const float* __restrict__ wqs, const float* __restrict__ wkc,
    const float* __restrict__ wvc, const float* __restrict__ wks,
    const float* __restrict__ wvs,
    ushort* __restrict__ sb, ushort* __restrict__ shb, ushort* __restrict__ hb,
    ushort* __restrict__ wqcb, ushort* __restrict__ wcatb, ushort* __restrict__ wvsb)
{
    unsigned e = (blockIdx.x * 256u + threadIdx.x) * 8u;
    if (e >= SEG8) return;
    const float* src; ushort* dst; unsigned off;
    if      (e < SEG0) { src = s;   dst = sb;             off = e; }
    else if (e < SEG1) { src = sh;  dst = shb;            off = e - SEG0; }
    else if (e < SEG2) { src = h;   dst = hb;             off = e - SEG1; }
    else if (e < SEG3) { src = wqc; dst = wqcb;           off = e - SEG2; }
    else if (e < SEG4) { src = wqs; dst = wcatb;          off = e - SEG3; }
    else if (e < SEG5) { src = wkc; dst = wcatb + 65536;  off = e - SEG4; }
    else if (e < SEG6) { src = wvc; dst = wcatb + 131072; off = e - SEG5; }
    else if (e < SEG7) { src = wks; dst = wcatb + 196608; off = e - SEG6; }
    else               { src = wvs; dst = wvsb;           off = e - SEG7; }
    float4 f0 = *(const float4*)&src[off];
    float4 f1 = *(const float4*)&src[off + 4];
    short8_t o;
    o[0] = f2bf(f0.x); o[1] = f2bf(f0.y); o[2] = f2bf(f0.z); o[3] = f2bf(f0.w);
    o[4] = f2bf(f1.x); o[5] = f2bf(f1.y); o[6] = f2bf(f1.z); o[7] = f2bf(f1.w);
    *(short8_t*)&dst[off] = o;
}

// ---------------------------------------------------------------------------
// GEMM tile body, round 16: global_load_lds width-16 staging into linear
// [128][64] LDS with XOR swizzle (both-sides): lane fetches global 16B-slot
// (l&7)^(row&7) so LDS[row][s] = G[row][s^(row&7)]; fragment reads use slot
// (4ks+g)^(R&7) -> banks spread across 8 groups (2-way alias only = free).
// Math (MFMA order, epilogue) identical to r15.
// ---------------------------------------------------------------------------
__device__ __forceinline__ void gemm_tile_body(
    const ushort* __restrict__ X, const ushort* __restrict__ W,
    ushort* __restrict__ d0, ushort* __restrict__ d1,
    ushort* __restrict__ d2, ushort* __restrict__ d3, int K,
    int m0, int n0, ushort (*Xs)[64], ushort (*Ws)[64])
{
    const int t = threadIdx.x;
    const int w = t >> 6, l = t & 63, c = l & 15, g = l >> 4;
    const int wr = w >> 1, wc = w & 1;
    const int r8 = l >> 3;                    // lane's row within 8-row group

    f32x4 acc[4][4] = {};

    for (int k0 = 0; k0 < K; k0 += 64) {
        __syncthreads();   // prior-iteration LDS reads complete
        #pragma unroll
        for (int q = 0; q < 4; ++q) {
            const int rbase = w * 32 + q * 8;        // wave-uniform
            const int row = rbase + r8;              // per-lane
            const int slot = (l & 7) ^ (row & 7);    // inverse-swizzled source
            gl_lds16(&X[(size_t)(m0 + row) * K + k0 + slot * 8], &Xs[rbase][0]);
            gl_lds16(&W[(size_t)(n0 + row) * K + k0 + slot * 8], &Ws[rbase][0]);
        }
        __syncthreads();   // compiler drains vmcnt before barrier
        #pragma unroll
        for (int ks = 0; ks < 2; ++ks) {
            short8_t af[4], bf[4];
            #pragma unroll
            for (int rt = 0; rt < 4; ++rt) {
                const int R = wr * 64 + rt * 16 + c;
                af[rt] = *(const short8_t*)&Xs[R][(((4 * ks + g) ^ (R & 7)) * 8)];
            }
            #pragma unroll
            for (int ct = 0; ct < 4; ++ct) {
                const int R = wc * 64 + ct * 16 + c;
                bf[ct] = *(const short8_t*)&Ws[R][(((4 * ks + g) ^ (R & 7)) * 8)];
            }
            #pragma unroll
            for (int rt = 0; rt < 4; ++rt)
                #pragma unroll
                for (int ct = 0; ct < 4; ++ct)
                    acc[rt][ct] = __builtin_amdgcn_mfma_f32_16x16x32_bf16(
                        af[rt], bf[ct], acc[rt][ct], 0, 0, 0);
        }
    }

    const int seg = n0 >> 8;
    ushort* dst = seg == 0 ? d0 : seg == 1 ? d1 : seg == 2 ? d2 : d3;
    const int colbase = (n0 & 255) + wc * 64;
    #pragma unroll
    for (int rt = 0; rt < 4; ++rt)
        #pragma unroll
        for (int ct = 0; ct < 4; ++ct)
            #pragma unroll
            for (int r = 0; r < 4; ++r) {
                int mrow = m0 + wr * 64 + rt * 16 + 4 * g + r;
                int col = colbase + ct * 16 + c;
                dst[(size_t)mrow * 256 + col] = f2bf(acc[rt][ct][r]);
            }
}

// ---------------------------------------------------------------------------
// v_s^T tile body (unchanged, verified).
// ---------------------------------------------------------------------------
__device__ __forceinline__ void vs_tile_body(
    const ushort* __restrict__ Wvs, const ushort* __restrict__ Hb,
    ushort* __restrict__ Cvt, int vbid)
{
    const int t = threadIdx.x;
    const int w = t >> 6, l = t & 63, c = l & 15, g = l >> 4;
    const int n0 = vbid * 256 + w * 64;

    f32x4 acc[4][4] = {};
    #pragma unroll
    for (int ks = 0; ks < 2; ++ks) {
        short8_t af[4], bfr[4];
        #pragma unroll
        for (int rt = 0; rt < 4; ++rt)
            af[rt] = *(const short8_t*)&Wvs[(size_t)(rt * 16 + c) * 64 + ks * 32 + 8 * g];
        #pragma unroll
        for (int ct = 0; ct < 4; ++ct)
            bfr[ct] = *(const short8_t*)&Hb[(size_t)(n0 + ct * 16 + c) * 64 + ks * 32 + 8 * g];
        #pragma unroll
        for (int rt = 0; rt < 4; ++rt)
            #pragma unroll
            for (int ct = 0; ct < 4; ++ct)
                acc[rt][ct] = __builtin_amdgcn_mfma_f32_16x16x32_bf16(
                    af[rt], bfr[ct], acc[rt][ct], 0, 0, 0);
    }
    #pragma unroll
    for (int rt = 0; rt < 4; ++rt)
        #pragma unroll
        for (int ct = 0; ct < 4; ++ct)
            #pragma unroll
            for (int r = 0; r < 4; ++r) {
                int cc = rt * 16 + 4 * g + r;
                int m  = n0 + ct * 16 + c;
                int b  = m >> 11, n = m & 2047;
                int L  = n * 64 + cc;
                int hh = L >> 15;
                int k  = (L & 32767) >> 4;
                int d  = L & 15;
                Cvt[(size_t)((b * 4 + hh) * 16 + d) * 2048 + k] = f2bf(acc[rt][ct][r]);
            }
}

// ---------------------------------------------------------------------------
// Fused projection dispatch: 672 blocks x 256 thr (routing as r15).
// ---------------------------------------------------------------------------
__global__ __launch_bounds__(256) void proj_all(
    const ushort* __restrict__ shb, const ushort* __restrict__ wcatb,
    ushort* __restrict__ Pqs, ushort* __restrict__ Pkc,
    ushort* __restrict__ Pvc, ushort* __restrict__ Pks,
    const ushort* __restrict__ sb, const ushort* __restrict__ wqcb,
    ushort* __restrict__ Pqc,
    const ushort* __restrict__ wvsb, const ushort* __restrict__ hb,
    ushort* __restrict__ PvsT)
{
    __shared__ ushort Xs[128][64];
    __shared__ ushort Ws[128][64];
    const int bid = blockIdx.x;
    if (bid < 512) {
        gemm_tile_body(shb, wcatb, Pqs, Pkc, Pvc, Pks, 256,
                       (bid >> 3) * 128, (bid & 7) * 128, Xs, Ws);
    } else if (bid < 640) {
        const int r = bid - 512;
        gemm_tile_body(sb, wqcb, Pqc, Pqc, Pqc, Pqc, 256,
                       (r >> 1) * 128, (r & 1) * 128, Xs, Ws);
    } else {
        vs_tile_body(wvsb, hb, PvsT, bid - 640);
    }
}

// ---------------------------------------------------------------------------
// Channel stage 1 (unchanged, verified).
// ---------------------------------------------------------------------------
__global__ __launch_bounds__(256) void chan_qk_partial(const ushort* __restrict__ Pqc,
                                                       const ushort* __restrict__ Pkc,
                                                       float* __restrict__ part)
{
    const int ch = blockIdx.x, hh = blockIdx.y, b = blockIdx.z;
    const ushort* Q = Pqc + (size_t)b * PROJ_EL + (size_t)hh * HEAD_EL;
    const ushort* Kk = Pkc + (size_t)b * PROJ_EL + (size_t)hh * HEAD_EL;
    __shared__ float Qs[64][68], Ks[64][68];
    const int t = threadIdx.x, ty = t >> 4, tx = t & 15;

    float acc[4][4] = {};
    for (int sub = 0; sub < 4; ++sub) {
        const int r0 = ch * 256 + sub * 64;
        __syncthreads();
        #pragma unroll
        for (int q = t; q < 512; q += 256) {
            int row = q >> 3, c8 = (q & 7) * 8;
            short8_t qv = *(const short8_t*)&Q[(size_t)(r0 + row) * 64 + c8];
            short8_t kv = *(const short8_t*)&Kk[(size_t)(r0 + row) * 64 + c8];
            #pragma unroll
            for (int j = 0; j < 8; ++j) {
                Qs[row][c8 + j] = bf2f((ushort)qv[j]);
                Ks[row][c8 + j] = bf2f((ushort)kv[j]);
            }
        }
        __syncthreads();
        #pragma unroll 8
        for (int nn = 0; nn < 64; ++nn) {
            float4 q4 = *(const float4*)&Qs[nn][ty * 4];
            float4 k4 = *(const float4*)&Ks[nn][tx * 4];
            float qa[4] = {q4.x, q4.y, q4.z, q4.w};
            float ka[4] = {k4.x, k4.y, k4.z, k4.w};
            #pragma unroll
            for (int ii = 0; ii < 4; ++ii)
                #pragma unroll
                for (int jj = 0; jj < 4; ++jj)
                    acc[ii][jj] += qa[ii] * ka[jj];
        }
    }
    float* P = part + (((size_t)(b * 4 + hh) * 8 + ch) << 12);
    #pragma unroll
    for (int ii = 0; ii < 4; ++ii)
        *(float4*)&P[(ty * 4 + ii) * 64 + tx * 4] =
            make_float4(acc[ii][0], acc[ii][1], acc[ii][2], acc[ii][3]);
}

// ---------------------------------------------------------------------------
// Channel stage 2 (r13 vectorized, verified).
// ---------------------------------------------------------------------------
__global__ __launch_bounds__(256) void chan_softmax(const float* __restrict__ part,
                                                    const float* __restrict__ temp,
                                                    ushort* __restrict__ Sca)
{
    const int bh = blockIdx.x;
    const int hsel = bh & 3;
    const int t = threadIdx.x;
    const int i = t >> 2, q = t & 3;
    const float sT = 0.125f * temp[hsel];

    float v[16];
    #pragma unroll
    for (int jj = 0; jj < 16; ++jj) v[jj] = 0.f;
    #pragma unroll
    for (int cc = 0; cc < 8; ++cc) {
        const float* p = &part[((size_t)bh * 8 + cc) * 4096 + i * 64 + q * 16];
        #pragma unroll
        for (int j4 = 0; j4 < 4; ++j4) {
            float4 f = *(const float4*)&p[j4 * 4];
            v[j4 * 4 + 0] += f.x; v[j4 * 4 + 1] += f.y;
            v[j4 * 4 + 2] += f.z; v[j4 * 4 + 3] += f.w;
        }
    }
    float m = -1e30f;
    #pragma unroll
    for (int jj = 0; jj < 16; ++jj) { v[jj] *= sT; m = fmaxf(m, v[jj]); }
    m = fmaxf(m, __shfl_xor(m, 1, 4));
    m = fmaxf(m, __shfl_xor(m, 2, 4));
    float sum = 0.f;
    #pragma unroll
    for (int jj = 0; jj < 16; ++jj) { v[jj] = __expf(v[jj] - m); sum += v[jj]; }
    sum += __shfl_xor(sum, 1, 4);
    sum += __shfl_xor(sum, 2, 4);
    const float inv = 1.0f / sum;
    ushort* dst = &Sca[((size_t)bh << 12) + i * 64 + q * 16];
    #pragma unroll
    for (int j4 = 0; j4 < 4; ++j4) {
        ushort4 r;
        r.x = f2bf(v[j4 * 4 + 0] * inv); r.y = f2bf(v[j4 * 4 + 1] * inv);
        r.z = f2bf(v[j4 * 4 + 2] * inv); r.w = f2bf(v[j4 * 4 + 3] * inv);
        *(ushort4*)&dst[j4 * 4] = r;
    }
}

// ---------------------------------------------------------------------------
// chan_pv wave-task body (unchanged, verified).
// ---------------------------------------------------------------------------
__device__ __forceinline__ void chan_pv_body(
    const ushort* __restrict__ Sca, const ushort* __restrict__ Pvc,
    float* __restrict__ out, int b, int hh, int nc, int wv, int l)
{
    const int c = l & 15, g = l >> 4;
    const ushort* S = Sca + ((size_t)(b * 4 + hh) << 12);
    const ushort* V = Pvc + (size_t)b * PROJ_EL + (size_t)hh * HEAD_EL;
    const int n0w = nc * 256 + wv * 64;

    f32x4 acc[4][4] = {};
    #pragma unroll
    for (int ks = 0; ks < 2; ++ks) {
        short8_t af[4], bfr[4];
        #pragma unroll
        for (int rt = 0; rt < 4; ++rt)
            af[rt] = *(const short8_t*)&S[(size_t)(rt * 16 + c) * 64 + ks * 32 + 8 * g];
        #pragma unroll
        for (int ct = 0; ct < 4; ++ct)
            bfr[ct] = *(const short8_t*)&V[(size_t)(n0w + ct * 16 + c) * 64 + ks * 32 + 8 * g];
        #pragma unroll
        for (int rt = 0; rt < 4; ++rt)
            #pragma unroll
            for (int ct = 0; ct < 4; ++ct)
                acc[rt][ct] = __builtin_amdgcn_mfma_f32_16x16x32_bf16(
                    af[rt], bfr[ct], acc[rt][ct], 0, 0, 0);
    }

    float* ob = out + (size_t)b * (Nn * 320);
    #pragma unroll
    for (int rt = 0; rt < 4; ++rt)
        #pragma unroll
        for (int ct = 0; ct < 4; ++ct)
            #pragma unroll
            for (int r = 0; r < 4; ++r) {
                int i = rt * 16 + 4 * g + r;
                int nn = n0w + ct * 16 + c;
                int rem = hh * 131072 + i * 2048 + nn;
                ob[(rem >> 8) * 320 + (rem & 255)] = acc[rt][ct][r];
            }
}

// ---------------------------------------------------------------------------
// Fused spatial + chan_pv dispatch (unchanged from r15, verified).
// ---------------------------------------------------------------------------
__global__ __launch_bounds__(512, 2) void spatial_pv(
    const ushort* __restrict__ Pqs, const ushort* __restrict__ Pks,
    const ushort* __restrict__ PvsT, const float* __restrict__ temp2,
    const ushort* __restrict__ Sca, const ushort* __restrict__ Pvc,
    float* __restrict__ out)
{
    if (blockIdx.x < 64) {
        const int task = blockIdx.x * 8 + (threadIdx.x >> 6);
        const int b2 = task >> 7, rem = task & 127;
        const int hh2 = rem >> 5, rem2 = rem & 31;
        const int nc = rem2 >> 2, wv = rem2 & 3;
        chan_pv_body(Sca, Pvc, out, b2, hh2, nc, wv, threadIdx.x & 63);
        return;
    }

    const int i0 = blockIdx.x - 64;
    const int xcd = i0 & 7, j = i0 >> 3;
    const int hsel = xcd + 8 * (j & 1);
    const int qb = j >> 1;
    const int b = hsel >> 2, hh = hsel & 3;

    const int t = threadIdx.x, w = t >> 6, l = t & 63;
    const int c = l & 15, g = l >> 4;
    const int qg = w >> 1, kh = w & 1;

    __shared__ ushort Kbuf[2][2][64][72];
    __shared__ ushort Vbuf[2][2][16][72];
    __shared__ ushort P_lds[8][2][16][72];
    __shared__ float  O_red[8][2][16][16];
    __shared__ float  L_red[8][2][16];

    const ushort* Qh = Pqs + (size_t)b * PROJ_EL + (size_t)hh * HEAD_EL;
    const ushort* Kh = Pks + (size_t)b * PROJ_EL + (size_t)hh * HEAD_EL;
    const ushort* Vt = PvsT + (size_t)((b * 4 + hh) * 16) * 2048;
    const float sT2 = 0.125f * temp2[hh] * 1.44269504f;

    const int q0 = qb * 128 + qg * 32;
    const ushort* qpA = Qh + (size_t)(q0 + c) * 64 + 8 * g;
    const ushort* qpB = qpA + 16 * 64;
    const short8_t qfA0 = *(const short8_t*)qpA;
    const short8_t qfA1 = *(const short8_t*)(qpA + 32);
    const short8_t qfB0 = *(const short8_t*)qpB;
    const short8_t qfB1 = *(const short8_t*)(qpB + 32);

    f32x4 oaccA = {0.f, 0.f, 0.f, 0.f}, oaccB = {0.f, 0.f, 0.f, 0.f};
    float lsumA = 0.f, lsumB = 0.f;
    ushort* PwA = &P_lds[w][0][0][0];
    ushort* PwB = &P_lds[w][1][0][0];

    const int sh_ = t >> 8, th = t & 255;
    const int krow = th >> 2, ksub = (th & 3) * 16;
    const int vrow = th >> 4, vcol = (th & 15) * 4;

    {
        const int kb = (sh_ * 16) * 64;
        short8_t k0 = *(const short8_t*)&Kh[(size_t)(kb + krow) * 64 + ksub];
        short8_t k1 = *(const short8_t*)&Kh[(size_t)(kb + krow) * 64 + ksub + 8];
        uint2 v0 = *(const uint2*)&Vt[(size_t)vrow * 2048 + kb + vcol];
        *(short8_t*)&Kbuf[sh_][0][krow][ksub]     = k0;
        *(short8_t*)&Kbuf[sh_][0][krow][ksub + 8] = k1;
        *(uint2*)&Vbuf[sh_][0][vrow][vcol] = v0;
    }

    short8_t kreg0, kreg1; uint2 vreg;
    for (int it = 0; it < 16; ++it) {
        const int cur = it & 1;

        if (it < 15) {
            const int nb = (sh_ * 16 + it + 1) * 64;
            kreg0 = *(const short8_t*)&Kh[(size_t)(nb + krow) * 64 + ksub];
            kreg1 = *(const short8_t*)&Kh[(size_t)(nb + krow) * 64 + ksub + 8];
            vreg = *(const uint2*)&Vt[(size_t)vrow * 2048 + nb + vcol];
        }

        __syncthreads();

        #pragma unroll
        for (int tc = 0; tc < 4; ++tc) {
            short8_t kf0 = *(const short8_t*)&Kbuf[kh][cur][tc * 16 + c][8 * g];
            short8_t kf1 = *(const short8_t*)&Kbuf[kh][cur][tc * 16 + c][32 + 8 * g];
            f32x4 z = {0.f, 0.f, 0.f, 0.f};
            f32x4 sa = __builtin_amdgcn_mfma_f32_16x16x32_bf16(kf0, qfA0, z, 0, 0, 0);
            sa = __builtin_amdgcn_mfma_f32_16x16x32_bf16(kf1, qfA1, sa, 0, 0, 0);
            f32x4 sb2 = __builtin_amdgcn_mfma_f32_16x16x32_bf16(kf0, qfB0, z, 0, 0, 0);
            sb2 = __builtin_amdgcn_mfma_f32_16x16x32_bf16(kf1, qfB1, sb2, 0, 0, 0);

            float a0 = __builtin_amdgcn_exp2f(sa[0] * sT2);
            float a1 = __builtin_amdgcn_exp2f(sa[1] * sT2);
            float a2 = __builtin_amdgcn_exp2f(sa[2] * sT2);
            float a3 = __builtin_amdgcn_exp2f(sa[3] * sT2);
            lsumA += (a0 + a1) + (a2 + a3);
            unsigned ua, ub;
            asm("v_cvt_pk_bf16_f32 %0, %1, %2" : "=v"(ua) : "v"(a0), "v"(a1));
            asm("v_cvt_pk_bf16_f32 %0, %1, %2" : "=v"(ub) : "v"(a2), "v"(a3));
            *(unsigned*)&PwA[(size_t)c * 72 + tc * 16 + 4 * g]     = ua;
            *(unsigned*)&PwA[(size_t)c * 72 + tc * 16 + 4 * g + 2] = ub;

            float b0 = __builtin_amdgcn_exp2f(sb2[0] * sT2);
            float b1 = __builtin_amdgcn_exp2f(sb2[1] * sT2);
            float b2 = __builtin_amdgcn_exp2f(sb2[2] * sT2);
            float b3 = __builtin_amdgcn_exp2f(sb2[3] * sT2);
            lsumB += (b0 + b1) + (b2 + b3);
            unsigned vb0, vb1;
            asm("v_cvt_pk_bf16_f32 %0, %1, %2" : "=v"(vb0) : "v"(b0), "v"(b1));
            asm("v_cvt_pk_bf16_f32 %0, %1, %2" : "=v"(vb1) : "v"(b2), "v"(b3));
            *(unsigned*)&PwB[(size_t)c * 72 + tc * 16 + 4 * g]     = vb0;
            *(unsigned*)&PwB[(size_t)c * 72 + tc * 16 + 4 * g + 2] = vb1;
        }
        __builtin_amdgcn_sched_barrier(0);
        #pragma unroll
        for (int ks = 0; ks < 2; ++ks) {
            short8_t vf = *(const short8_t*)&Vbuf[kh][cur][c][ks * 32 + 8 * g];
            short8_t pfA = *(const short8_t*)&PwA[(size_t)c * 72 + ks * 32 + 8 * g];
            oaccA = __builtin_amdgcn_mfma_f32_16x16x32_bf16(vf, pfA, oaccA, 0, 0, 0);
            short8_t pfB = *(const short8_t*)&PwB[(size_t)c * 72 + ks * 32 + 8 * g];
            oaccB = __builtin_amdgcn_mfma_f32_16x16x32_bf16(vf, pfB, oaccB, 0, 0, 0);
        }

        if (it < 15) {
            *(short8_t*)&Kbuf[sh_][cur ^ 1][krow][ksub]     = kreg0;
            *(short8_t*)&Kbuf[sh_][cur ^ 1][krow][ksub + 8] = kreg1;
            *(uint2*)&Vbuf[sh_][cur ^ 1][vrow][vcol] = vreg;
        }
    }

    lsumA += __shfl_xor(lsumA, 16);
    lsumA += __shfl_xor(lsumA, 32);
    lsumB += __shfl_xor(lsumB, 16);
    lsumB += __shfl_xor(lsumB, 32);

    *(float4*)&O_red[w][0][c][4 * g] = make_float4(oaccA[0], oaccA[1], oaccA[2], oaccA[3]);
    *(float4*)&O_red[w][1][c][4 * g] = make_float4(oaccB[0], oaccB[1], oaccB[2], oaccB[3]);
    if (g == 0) { L_red[w][0][c] = lsumA; L_red[w][1][c] = lsumB; }
    __syncthreads();

    if (kh == 0) {
        #pragma unroll
        for (int ss = 0; ss < 2; ++ss) {
            float4 o0 = *(const float4*)&O_red[w][ss][c][4 * g];
            float4 o1 = *(const float4*)&O_red[w + 1][ss][c][4 * g];
            float ltot = L_red[w][ss][c] + L_red[w + 1][ss][c];
            const float inv = 1.0f / ltot;
            const int nn = q0 + ss * 16 + c;
            const int n = hh * 512 + (nn >> 2);
            const int cc = 256 + ((nn & 3) << 4) + 4 * g;
            float4 o4 = make_float4((o0.x + o1.x) * inv, (o0.y + o1.y) * inv,
                                    (o0.z + o1.z) * inv, (o0.w + o1.w) * inv);
            *(float4*)&out[((size_t)b * Nn + n) * 320 + cc] = o4;
        }
    }
}

// ---------------------------------------------------------------------------
extern "C" void kernel_launch(void* const* d_in, const int* in_sizes, int n_in,
                              void* d_out, int out_size, void* d_ws, size_t ws_size,
                              hipStream_t stream)
{
    const float* s     = (const float*)d_in[0];
    const float* h     = (const float*)d_in[1];
    const float* sh    = (const float*)d_in[2];
    const float* temp  = (const float*)d_in[3];
    const float* temp2 = (const float*)d_in[4];
    const float* Wq_c  = (const float*)d_in[5];
    const float* Wq_s  = (const float*)d_in[6];
    const float* Wk_c  = (const float*)d_in[7];
    const float* Wv_c  = (const float*)d_in[8];
    const float* Wk_s  = (const float*)d_in[9];
    const float* Wv_s  = (const float*)d_in[10];
    float* out = (float*)d_out;
    float* ws = (float*)d_ws;

    ushort* sb    = (ushort*)(ws + OFF_SB);
    ushort* shb   = (ushort*)(ws + OFF_SHB);
    ushort* hb    = (ushort*)(ws + OFF_HB);
    ushort* wqcb  = (ushort*)(ws + OFF_WQC);
    ushort* wcatb = (ushort*)(ws + OFF_WCAT);
    ushort* wvsb  = (ushort*)(ws + OFF_WVS);
    ushort* Pqc   = (ushort*)(ws + OFF_PQC);
    ushort* Pqs   = (ushort*)(ws + OFF_PQS);
    ushort* Pkc   = (ushort*)(ws + OFF_PKC);
    ushort* Pvc   = (ushort*)(ws + OFF_PVC);
    ushort* Pks   = (ushort*)(ws + OFF_PKS);
    ushort* PvsT  = (ushort*)(ws + OFF_PVST);
    float*  part  = ws + OFF_PART;
    ushort* Sca   = (ushort*)(ws + OFF_SCA);

    const dim3 blk(256);

    // 1) f32 -> bf16 conversions
    convert_all<<<dim3((SEG8 / 8 + 255) / 256), blk, 0, stream>>>(
        s, sh, h, Wq_c, Wq_s, Wk_c, Wv_c, Wk_s, Wv_s,
        sb, shb, hb, wqcb, wcatb, wvsb);

    // 2) all projections in ONE dispatch (gload_lds + XOR-swizzle staging)
    proj_all<<<dim3(672), blk, 0, stream>>>(
        shb, wcatb, Pqs, Pkc, Pvc, Pks, sb, wqcb, Pqc, wvsb, hb, PvsT);

    // 3) channel branch stages 1-2
    chan_qk_partial<<<dim3(8, 4, 4), blk, 0, stream>>>(Pqc, Pkc, part);
    chan_softmax<<<dim3(16), blk, 0, stream>>>(part, temp, Sca);

    // 4) fused spatial + chan_pv
    spatial_pv<<<dim3(320), dim3(512), 0, stream>>>(
        Pqs, Pks, PvsT, temp2, Sca, Pvc, out);
}

// Round 17
// 59.706 us; speedup vs baseline: 1.6359x; 1.1183x over previous
//
#include <hip/hip_runtime.h>
#include <math.h>

// ---------------------------------------------------------------------------
// WCSA round 17 = round 16 (passing, 66.8us) + ONE change: chan_qk_partial
// -> MFMA (was f32 VALU, ~6us at 0.5 blocks/CU). Q^T/K^T staged transposed
// into padded LDS (conflict-free scalar writes: thread-per-row mapping);
// A-frag = Q^T rows, B-frag = K^T rows, acc over the chunk's 256 n's;
// epilogue writes the identical `part` layout. All else verbatim r16.
// ---------------------------------------------------------------------------

constexpr int Bb = 4, Nn = 2048, Hh = 4;
constexpr int PROJ_EL = Nn * 256;
constexpr int HEAD_EL = Nn * 64;

typedef __attribute__((ext_vector_type(8))) short short8_t;   // 8 bf16
typedef __attribute__((ext_vector_type(4))) float f32x4;

__device__ __forceinline__ ushort f2bf(float x) {
    union { float f; unsigned u; } v; v.f = x;
    unsigned r = v.u + 0x7fffu + ((v.u >> 16) & 1u);   // RNE
    return (ushort)(r >> 16);
}
__device__ __forceinline__ float bf2f(ushort x) {
    union { unsigned u; float f; } v; v.u = ((unsigned)x) << 16;
    return v.f;
}
// async global->LDS, 16B/lane; LDS dest = wave-uniform base + lane*16
__device__ __forceinline__ void gl_lds16(const ushort* g, ushort* l) {
    __builtin_amdgcn_global_load_lds(
        (const __attribute__((address_space(1))) void*)g,
        (__attribute__((address_space(3))) void*)l, 16, 0, 0);
}

// ---------------- workspace layout (float granularity) ---------------------
constexpr size_t OFF_SB    = 0;
constexpr size_t OFF_SHB   = OFF_SB   + 1024 * 1024;
constexpr size_t OFF_HB    = OFF_SHB  + 1024 * 1024;
constexpr size_t OFF_WQC   = OFF_HB   + 256 * 1024;
constexpr size_t OFF_WCAT  = OFF_WQC  + 32 * 1024;
constexpr size_t OFF_PQC   = OFF_WCAT + 128 * 1024;
constexpr size_t OFF_PQS   = OFF_PQC  + 1024 * 1024;
constexpr size_t OFF_PKC   = OFF_PQS  + 1024 * 1024;
constexpr size_t OFF_PVC   = OFF_PKC  + 1024 * 1024;
constexpr size_t OFF_PKS   = OFF_PVC  + 1024 * 1024;
constexpr size_t OFF_PVST  = OFF_PKS  + 1024 * 1024;
constexpr size_t OFF_PART  = OFF_PVST + 256 * 1024;
constexpr size_t OFF_SCA   = OFF_PART + 512 * 1024;
constexpr size_t OFF_WVS   = OFF_SCA  + 32 * 1024;

// ---------------------------------------------------------------------------
// Convert all needed f32 arrays to bf16 in one pass (unchanged, verified).
// ---------------------------------------------------------------------------
constexpr unsigned SEG0 = 2097152;
constexpr unsigned SEG1 = SEG0 + 2097152;
constexpr unsigned SEG2 = SEG1 + 524288;
constexpr unsigned SEG3 = SEG2 + 65536;
constexpr unsigned SEG4 = SEG3 + 65536;
constexpr unsigned SEG5 = SEG4 + 65536;
constexpr unsigned SEG6 = SEG5 + 65536;
constexpr unsigned SEG7 = SEG6 + 65536;
constexpr unsigned SEG8 = SEG7 + 4096;

__global__ __launch_bounds__(256) void convert_all(
    const float* __restrict__ s, const float* __restrict__ sh,
    const float* __restrict__ h, const float* __restrict__ wqc,
    const float* __restrict__ wqs, const float* __restrict__ wkc,
    const float* __restrict__ wvc, const float* __restrict__ wks,
    const float* __restrict__ wvs,
    ushort* __restrict__ sb, ushort* __restrict__ shb, ushort* __restrict__ hb,
    ushort* __restrict__ wqcb, ushort* __restrict__ wcatb, ushort* __restrict__ wvsb)
{
    unsigned e = (blockIdx.x * 256u + threadIdx.x) * 8u;
    if (e >= SEG8) return;
    const float* src; ushort* dst; unsigned off;
    if      (e < SEG0) { src = s;   dst = sb;             off = e; }
    else if (e < SEG1) { src = sh;  dst = shb;            off = e - SEG0; }
    else if (e < SEG2) { src = h;   dst = hb;             off = e - SEG1; }
    else if (e < SEG3) { src = wqc; dst = wqcb;           off = e - SEG2; }
    else if (e < SEG4) { src = wqs; dst = wcatb;          off = e - SEG3; }
    else if (e < SEG5) { src = wkc; dst = wcatb + 65536;  off = e - SEG4; }
    else if (e < SEG6) { src = wvc; dst = wcatb + 131072; off = e - SEG5; }
    else if (e < SEG7) { src = wks; dst = wcatb + 196608; off = e - SEG6; }
    else               { src = wvs; dst = wvsb;           off = e - SEG7; }
    float4 f0 = *(const float4*)&src[off];
    float4 f1 = *(const float4*)&src[off + 4];
    short8_t o;
    o[0] = f2bf(f0.x); o[1] = f2bf(f0.y); o[2] = f2bf(f0.z); o[3] = f2bf(f0.w);
    o[4] = f2bf(f1.x); o[5] = f2bf(f1.y); o[6] = f2bf(f1.z); o[7] = f2bf(f1.w);
    *(short8_t*)&dst[off] = o;
}

// ---------------------------------------------------------------------------
// GEMM tile body (r16 gload_lds + XOR swizzle, verified).
// ---------------------------------------------------------------------------
__device__ __forceinline__ void gemm_tile_body(
    const ushort* __restrict__ X, const ushort* __restrict__ W,
    ushort* __restrict__ d0, ushort* __restrict__ d1,
    ushort* __restrict__ d2, ushort* __restrict__ d3, int K,
    int m0, int n0, ushort (*Xs)[64], ushort (*Ws)[64])
{
    const int t = threadIdx.x;
    const int w = t >> 6, l = t & 63, c = l & 15, g = l >> 4;
    const int wr = w >> 1, wc = w & 1;
    const int r8 = l >> 3;

    f32x4 acc[4][4] = {};

    for (int k0 = 0; k0 < K; k0 += 64) {
        __syncthreads();
        #pragma unroll
        for (int q = 0; q < 4; ++q) {
            const int rbase = w * 32 + q * 8;
            const int row = rbase + r8;
            const int slot = (l & 7) ^ (row & 7);
            gl_lds16(&X[(size_t)(m0 + row) * K + k0 + slot * 8], &Xs[rbase][0]);
            gl_lds16(&W[(size_t)(n0 + row) * K + k0 + slot * 8], &Ws[rbase][0]);
        }
        __syncthreads();
        #pragma unroll
        for (int ks = 0; ks < 2; ++ks) {
            short8_t af[4], bf[4];
            #pragma unroll
            for (int rt = 0; rt < 4; ++rt) {
                const int R = wr * 64 + rt * 16 + c;
                af[rt] = *(const short8_t*)&Xs[R][(((4 * ks + g) ^ (R & 7)) * 8)];
            }
            #pragma unroll
            for (int ct = 0; ct < 4; ++ct) {
                const int R = wc * 64 + ct * 16 + c;
                bf[ct] = *(const short8_t*)&Ws[R][(((4 * ks + g) ^ (R & 7)) * 8)];
            }
            #pragma unroll
            for (int rt = 0; rt < 4; ++rt)
                #pragma unroll
                for (int ct = 0; ct < 4; ++ct)
                    acc[rt][ct] = __builtin_amdgcn_mfma_f32_16x16x32_bf16(
                        af[rt], bf[ct], acc[rt][ct], 0, 0, 0);
        }
    }

    const int seg = n0 >> 8;
    ushort* dst = seg == 0 ? d0 : seg == 1 ? d1 : seg == 2 ? d2 : d3;
    const int colbase = (n0 & 255) + wc * 64;
    #pragma unroll
    for (int rt = 0; rt < 4; ++rt)
        #pragma unroll
        for (int ct = 0; ct < 4; ++ct)
            #pragma unroll
            for (int r = 0; r < 4; ++r) {
                int mrow = m0 + wr * 64 + rt * 16 + 4 * g + r;
                int col = colbase + ct * 16 + c;
                dst[(size_t)mrow * 256 + col] = f2bf(acc[rt][ct][r]);
            }
}

// ---------------------------------------------------------------------------
// v_s^T tile body (unchanged, verified).
// ---------------------------------------------------------------------------
__device__ __forceinline__ void vs_tile_body(
    const ushort* __restrict__ Wvs, const ushort* __restrict__ Hb,
    ushort* __restrict__ Cvt, int vbid)
{
    const int t = threadIdx.x;
    const int w = t >> 6, l = t & 63, c = l & 15, g = l >> 4;
    const int n0 = vbid * 256 + w * 64;

    f32x4 acc[4][4] = {};
    #pragma unroll
    for (int ks = 0; ks < 2; ++ks) {
        short8_t af[4], bfr[4];
        #pragma unroll
        for (int rt = 0; rt < 4; ++rt)
            af[rt] = *(const short8_t*)&Wvs[(size_t)(rt * 16 + c) * 64 + ks * 32 + 8 * g];
        #pragma unroll
        for (int ct = 0; ct < 4; ++ct)
            bfr[ct] = *(const short8_t*)&Hb[(size_t)(n0 + ct * 16 + c) * 64 + ks * 32 + 8 * g];
        #pragma unroll
        for (int rt = 0; rt < 4; ++rt)
            #pragma unroll
            for (int ct = 0; ct < 4; ++ct)
                acc[rt][ct] = __builtin_amdgcn_mfma_f32_16x16x32_bf16(
                    af[rt], bfr[ct], acc[rt][ct], 0, 0, 0);
    }
    #pragma unroll
    for (int rt = 0; rt < 4; ++rt)
        #pragma unroll
        for (int ct = 0; ct < 4; ++ct)
            #pragma unroll
            for (int r = 0; r < 4; ++r) {
                int cc = rt * 16 + 4 * g + r;
                int m  = n0 + ct * 16 + c;
                int b  = m >> 11, n = m & 2047;
                int L  = n * 64 + cc;
                int hh = L >> 15;
                int k  = (L & 32767) >> 4;
                int d  = L & 15;
                Cvt[(size_t)((b * 4 + hh) * 16 + d) * 2048 + k] = f2bf(acc[rt][ct][r]);
            }
}

// ---------------------------------------------------------------------------
// Fused projection dispatch (r16 routing, verified).
// ---------------------------------------------------------------------------
__global__ __launch_bounds__(256) void proj_all(
    const ushort* __restrict__ shb, const ushort* __restrict__ wcatb,
    ushort* __restrict__ Pqs, ushort* __restrict__ Pkc,
    ushort* __restrict__ Pvc, ushort* __restrict__ Pks,
    const ushort* __restrict__ sb, const ushort* __restrict__ wqcb,
    ushort* __restrict__ Pqc,
    const ushort* __restrict__ wvsb, const ushort* __restrict__ hb,
    ushort* __restrict__ PvsT)
{
    __shared__ ushort Xs[128][64];
    __shared__ ushort Ws[128][64];
    const int bid = blockIdx.x;
    if (bid < 512) {
        gemm_tile_body(shb, wcatb, Pqs, Pkc, Pvc, Pks, 256,
                       (bid >> 3) * 128, (bid & 7) * 128, Xs, Ws);
    } else if (bid < 640) {
        const int r = bid - 512;
        gemm_tile_body(sb, wqcb, Pqc, Pqc, Pqc, Pqc, 256,
                       (r >> 1) * 128, (r & 1) * 128, Xs, Ws);
    } else {
        vs_tile_body(wvsb, hb, PvsT, bid - 640);
    }
}

// ---------------------------------------------------------------------------
// Channel stage 1, round 17: MFMA. Per (b,h,chunk of 256 n): 4 subtiles of
// 64 n. Stage Q^T, K^T (channel-major [64][72], thread-per-row writes =
// conflict-free); A-frag = Q^T rows (channels i), B-frag = K^T rows
// (channels j); C[i][j] = sum_n Q[n][i] K[n][j] accumulated over the chunk.
// Epilogue writes the same `part` layout as before.
// ---------------------------------------------------------------------------
__global__ __launch_bounds__(256) void chan_qk_mfma(const ushort* __restrict__ Pqc,
                                                    const ushort* __restrict__ Pkc,
                                                    float* __restrict__ part)
{
    const int ch = blockIdx.x, hh = blockIdx.y, b = blockIdx.z;
    const ushort* Q = Pqc + (size_t)b * PROJ_EL + (size_t)hh * HEAD_EL;
    const ushort* Kk = Pkc + (size_t)b * PROJ_EL + (size_t)hh * HEAD_EL;
    __shared__ ushort Qt[64][72];   // [channel][n_local]
    __shared__ ushort Kt[64][72];
    const int t = threadIdx.x;
    const int w = t >> 6, l = t & 63, c = l & 15, g = l >> 4;
    const int srow = t & 63;                // n_local staged by this thread
    const int scol0 = (t >> 6) * 8;         // channel group base

    f32x4 acc[4] = {};                      // wave w owns row-tile w; 4 col-tiles

    for (int sub = 0; sub < 4; ++sub) {
        const int r0 = ch * 256 + sub * 64;
        __syncthreads();
        #pragma unroll
        for (int pass = 0; pass < 2; ++pass) {
            const int cbase = scol0 + pass * 32;
            short8_t qv = *(const short8_t*)&Q[(size_t)(r0 + srow) * 64 + cbase];
            short8_t kv = *(const short8_t*)&Kk[(size_t)(r0 + srow) * 64 + cbase];
            #pragma unroll
            for (int j = 0; j < 8; ++j) {
                Qt[cbase + j][srow] = (ushort)qv[j];
                Kt[cbase + j][srow] = (ushort)kv[j];
            }
        }
        __syncthreads();
        #pragma unroll
        for (int ks = 0; ks < 2; ++ks) {
            short8_t af = *(const short8_t*)&Qt[w * 16 + c][ks * 32 + 8 * g];
            #pragma unroll
            for (int ct = 0; ct < 4; ++ct) {
                short8_t bf = *(const short8_t*)&Kt[ct * 16 + c][ks * 32 + 8 * g];
                acc[ct] = __builtin_amdgcn_mfma_f32_16x16x32_bf16(af, bf, acc[ct], 0, 0, 0);
            }
        }
    }

    float* P = part + (((size_t)(b * 4 + hh) * 8 + ch) << 12);
    #pragma unroll
    for (int ct = 0; ct < 4; ++ct)
        #pragma unroll
        for (int r = 0; r < 4; ++r)
            P[(w * 16 + 4 * g + r) * 64 + ct * 16 + c] = acc[ct][r];
}

// ---------------------------------------------------------------------------
// Channel stage 2 (r13 vectorized, verified).
// ---------------------------------------------------------------------------
__global__ __launch_bounds__(256) void chan_softmax(const float* __restrict__ part,
                                                    const float* __restrict__ temp,
                                                    ushort* __restrict__ Sca)
{
    const int bh = blockIdx.x;
    const int hsel = bh & 3;
    const int t = threadIdx.x;
    const int i = t >> 2, q = t & 3;
    const float sT = 0.125f * temp[hsel];

    float v[16];
    #pragma unroll
    for (int jj = 0; jj < 16; ++jj) v[jj] = 0.f;
    #pragma unroll
    for (int cc = 0; cc < 8; ++cc) {
        const float* p = &part[((size_t)bh * 8 + cc) * 4096 + i * 64 + q * 16];
        #pragma unroll
        for (int j4 = 0; j4 < 4; ++j4) {
            float4 f = *(const float4*)&p[j4 * 4];
            v[j4 * 4 + 0] += f.x; v[j4 * 4 + 1] += f.y;
            v[j4 * 4 + 2] += f.z; v[j4 * 4 + 3] += f.w;
        }
    }
    float m = -1e30f;
    #pragma unroll
    for (int jj = 0; jj < 16; ++jj) { v[jj] *= sT; m = fmaxf(m, v[jj]); }
    m = fmaxf(m, __shfl_xor(m, 1, 4));
    m = fmaxf(m, __shfl_xor(m, 2, 4));
    float sum = 0.f;
    #pragma unroll
    for (int jj = 0; jj < 16; ++jj) { v[jj] = __expf(v[jj] - m); sum += v[jj]; }
    sum += __shfl_xor(sum, 1, 4);
    sum += __shfl_xor(sum, 2, 4);
    const float inv = 1.0f / sum;
    ushort* dst = &Sca[((size_t)bh << 12) + i * 64 + q * 16];
    #pragma unroll
    for (int j4 = 0; j4 < 4; ++j4) {
        ushort4 r;
        r.x = f2bf(v[j4 * 4 + 0] * inv); r.y = f2bf(v[j4 * 4 + 1] * inv);
        r.z = f2bf(v[j4 * 4 + 2] * inv); r.w = f2bf(v[j4 * 4 + 3] * inv);
        *(ushort4*)&dst[j4 * 4] = r;
    }
}

// ---------------------------------------------------------------------------
// chan_pv wave-task body (unchanged, verified).
// ---------------------------------------------------------------------------
__device__ __forceinline__ void chan_pv_body(
    const ushort* __restrict__ Sca, const ushort* __restrict__ Pvc,
    float* __restrict__ out, int b, int hh, int nc, int wv, int l)
{
    const int c = l & 15, g = l >> 4;
    const ushort* S = Sca + ((size_t)(b * 4 + hh) << 12);
    const ushort* V = Pvc + (size_t)b * PROJ_EL + (size_t)hh * HEAD_EL;
    const int n0w = nc * 256 + wv * 64;

    f32x4 acc[4][4] = {};
    #pragma unroll
    for (int ks = 0; ks < 2; ++ks) {
        short8_t af[4], bfr[4];
        #pragma unroll
        for (int rt = 0; rt < 4; ++rt)
            af[rt] = *(const short8_t*)&S[(size_t)(rt * 16 + c) * 64 + ks * 32 + 8 * g];
        #pragma unroll
        for (int ct = 0; ct < 4; ++ct)
            bfr[ct] = *(const short8_t*)&V[(size_t)(n0w + ct * 16 + c) * 64 + ks * 32 + 8 * g];
        #pragma unroll
        for (int rt = 0; rt < 4; ++rt)
            #pragma unroll
            for (int ct = 0; ct < 4; ++ct)
                acc[rt][ct] = __builtin_amdgcn_mfma_f32_16x16x32_bf16(
                    af[rt], bfr[ct], acc[rt][ct], 0, 0, 0);
    }

    float* ob = out + (size_t)b * (Nn * 320);
    #pragma unroll
    for (int rt = 0; rt < 4; ++rt)
        #pragma unroll
        for (int ct = 0; ct < 4; ++ct)
            #pragma unroll
            for (int r = 0; r < 4; ++r) {
                int i = rt * 16 + 4 * g + r;
                int nn = n0w + ct * 16 + c;
                int rem = hh * 131072 + i * 2048 + nn;
                ob[(rem >> 8) * 320 + (rem & 255)] = acc[rt][ct][r];
            }
}

// ---------------------------------------------------------------------------
// Fused spatial + chan_pv dispatch (unchanged from r15/r16, verified).
// ---------------------------------------------------------------------------
__global__ __launch_bounds__(512, 2) void spatial_pv(
    const ushort* __restrict__ Pqs, const ushort* __restrict__ Pks,
    const ushort* __restrict__ PvsT, const float* __restrict__ temp2,
    const ushort* __restrict__ Sca, const ushort* __restrict__ Pvc,
    float* __restrict__ out)
{
    if (blockIdx.x < 64) {
        const int task = blockIdx.x * 8 + (threadIdx.x >> 6);
        const int b2 = task >> 7, rem = task & 127;
        const int hh2 = rem >> 5, rem2 = rem & 31;
        const int nc = rem2 >> 2, wv = rem2 & 3;
        chan_pv_body(Sca, Pvc, out, b2, hh2, nc, wv, threadIdx.x & 63);
        return;
    }

    const int i0 = blockIdx.x - 64;
    const int xcd = i0 & 7, j = i0 >> 3;
    const int hsel = xcd + 8 * (j & 1);
    const int qb = j >> 1;
    const int b = hsel >> 2, hh = hsel & 3;

    const int t = threadIdx.x, w = t >> 6, l = t & 63;
    const int c = l & 15, g = l >> 4;
    const int qg = w >> 1, kh = w & 1;

    __shared__ ushort Kbuf[2][2][64][72];
    __shared__ ushort Vbuf[2][2][16][72];
    __shared__ ushort P_lds[8][2][16][72];
    __shared__ float  O_red[8][2][16][16];
    __shared__ float  L_red[8][2][16];

    const ushort* Qh = Pqs + (size_t)b * PROJ_EL + (size_t)hh * HEAD_EL;
    const ushort* Kh = Pks + (size_t)b * PROJ_EL + (size_t)hh * HEAD_EL;
    const ushort* Vt = PvsT + (size_t)((b * 4 + hh) * 16) * 2048;
    const float sT2 = 0.125f * temp2[hh] * 1.44269504f;

    const int q0 = qb * 128 + qg * 32;
    const ushort* qpA = Qh + (size_t)(q0 + c) * 64 + 8 * g;
    const ushort* qpB = qpA + 16 * 64;
    const short8_t qfA0 = *(const short8_t*)qpA;
    const short8_t qfA1 = *(const short8_t*)(qpA + 32);
    const short8_t qfB0 = *(const short8_t*)qpB;
    const short8_t qfB1 = *(const short8_t*)(qpB + 32);

    f32x4 oaccA = {0.f, 0.f, 0.f, 0.f}, oaccB = {0.f, 0.f, 0.f, 0.f};
    float lsumA = 0.f, lsumB = 0.f;
    ushort* PwA = &P_lds[w][0][0][0];
    ushort* PwB = &P_lds[w][1][0][0];

    const int sh_ = t >> 8, th = t & 255;
    const int krow = th >> 2, ksub = (th & 3) * 16;
    const int vrow = th >> 4, vcol = (th & 15) * 4;

    {
        const int kb = (sh_ * 16) * 64;
        short8_t k0 = *(const short8_t*)&Kh[(size_t)(kb + krow) * 64 + ksub];
        short8_t k1 = *(const short8_t*)&Kh[(size_t)(kb + krow) * 64 + ksub + 8];
        uint2 v0 = *(const uint2*)&Vt[(size_t)vrow * 2048 + kb + vcol];
        *(short8_t*)&Kbuf[sh_][0][krow][ksub]     = k0;
        *(short8_t*)&Kbuf[sh_][0][krow][ksub + 8] = k1;
        *(uint2*)&Vbuf[sh_][0][vrow][vcol] = v0;
    }

    short8_t kreg0, kreg1; uint2 vreg;
    for (int it = 0; it < 16; ++it) {
        const int cur = it & 1;

        if (it < 15) {
            const int nb = (sh_ * 16 + it + 1) * 64;
            kreg0 = *(const short8_t*)&Kh[(size_t)(nb + krow) * 64 + ksub];
            kreg1 = *(const short8_t*)&Kh[(size_t)(nb + krow) * 64 + ksub + 8];
            vreg = *(const uint2*)&Vt[(size_t)vrow * 2048 + nb + vcol];
        }

        __syncthreads();

        #pragma unroll
        for (int tc = 0; tc < 4; ++tc) {
            short8_t kf0 = *(const short8_t*)&Kbuf[kh][cur][tc * 16 + c][8 * g];
            short8_t kf1 = *(const short8_t*)&Kbuf[kh][cur][tc * 16 + c][32 + 8 * g];
            f32x4 z = {0.f, 0.f, 0.f, 0.f};
            f32x4 sa = __builtin_amdgcn_mfma_f32_16x16x32_bf16(kf0, qfA0, z, 0, 0, 0);
            sa = __builtin_amdgcn_mfma_f32_16x16x32_bf16(kf1, qfA1, sa, 0, 0, 0);
            f32x4 sb2 = __builtin_amdgcn_mfma_f32_16x16x32_bf16(kf0, qfB0, z, 0, 0, 0);
            sb2 = __builtin_amdgcn_mfma_f32_16x16x32_bf16(kf1, qfB1, sb2, 0, 0, 0);

            float a0 = __builtin_amdgcn_exp2f(sa[0] * sT2);
            float a1 = __builtin_amdgcn_exp2f(sa[1] * sT2);
            float a2 = __builtin_amdgcn_exp2f(sa[2] * sT2);
            float a3 = __builtin_amdgcn_exp2f(sa[3] * sT2);
            lsumA += (a0 + a1) + (a2 + a3);
            unsigned ua, ub;
            asm("v_cvt_pk_bf16_f32 %0, %1, %2" : "=v"(ua) : "v"(a0), "v"(a1));
            asm("v_cvt_pk_bf16_f32 %0, %1, %2" : "=v"(ub) : "v"(a2), "v"(a3));
            *(unsigned*)&PwA[(size_t)c * 72 + tc * 16 + 4 * g]     = ua;
            *(unsigned*)&PwA[(size_t)c * 72 + tc * 16 + 4 * g + 2] = ub;

            float b0 = __builtin_amdgcn_exp2f(sb2[0] * sT2);
            float b1 = __builtin_amdgcn_exp2f(sb2[1] * sT2);
            float b2 = __builtin_amdgcn_exp2f(sb2[2] * sT2);
            float b3 = __builtin_amdgcn_exp2f(sb2[3] * sT2);
            lsumB += (b0 + b1) + (b2 + b3);
            unsigned vb0, vb1;
            asm("v_cvt_pk_bf16_f32 %0, %1, %2" : "=v"(vb0) : "v"(b0), "v"(b1));
            asm("v_cvt_pk_bf16_f32 %0, %1, %2" : "=v"(vb1) : "v"(b2), "v"(b3));
            *(unsigned*)&PwB[(size_t)c * 72 + tc * 16 + 4 * g]     = vb0;
            *(unsigned*)&PwB[(size_t)c * 72 + tc * 16 + 4 * g + 2] = vb1;
        }
        __builtin_amdgcn_sched_barrier(0);
        #pragma unroll
        for (int ks = 0; ks < 2; ++ks) {
            short8_t vf = *(const short8_t*)&Vbuf[kh][cur][c][ks * 32 + 8 * g];
            short8_t pfA = *(const short8_t*)&PwA[(size_t)c * 72 + ks * 32 + 8 * g];
            oaccA = __builtin_amdgcn_mfma_f32_16x16x32_bf16(vf, pfA, oaccA, 0, 0, 0);
            short8_t pfB = *(const short8_t*)&PwB[(size_t)c * 72 + ks * 32 + 8 * g];
            oaccB = __builtin_amdgcn_mfma_f32_16x16x32_bf16(vf, pfB, oaccB, 0, 0, 0);
        }

        if (it < 15) {
            *(short8_t*)&Kbuf[sh_][cur ^ 1][krow][ksub]     = kreg0;
            *(short8_t*)&Kbuf[sh_][cur ^ 1][krow][ksub + 8] = kreg1;
            *(uint2*)&Vbuf[sh_][cur ^ 1][vrow][vcol] = vreg;
        }
    }

    lsumA += __shfl_xor(lsumA, 16);
    lsumA += __shfl_xor(lsumA, 32);
    lsumB += __shfl_xor(lsumB, 16);
    lsumB += __shfl_xor(lsumB, 32);

    *(float4*)&O_red[w][0][c][4 * g] = make_float4(oaccA[0], oaccA[1], oaccA[2], oaccA[3]);
    *(float4*)&O_red[w][1][c][4 * g] = make_float4(oaccB[0], oaccB[1], oaccB[2], oaccB[3]);
    if (g == 0) { L_red[w][0][c] = lsumA; L_red[w][1][c] = lsumB; }
    __syncthreads();

    if (kh == 0) {
        #pragma unroll
        for (int ss = 0; ss < 2; ++ss) {
            float4 o0 = *(const float4*)&O_red[w][ss][c][4 * g];
            float4 o1 = *(const float4*)&O_red[w + 1][ss][c][4 * g];
            float ltot = L_red[w][ss][c] + L_red[w + 1][ss][c];
            const float inv = 1.0f / ltot;
            const int nn = q0 + ss * 16 + c;
            const int n = hh * 512 + (nn >> 2);
            const int cc = 256 + ((nn & 3) << 4) + 4 * g;
            float4 o4 = make_float4((o0.x + o1.x) * inv, (o0.y + o1.y) * inv,
                                    (o0.z + o1.z) * inv, (o0.w + o1.w) * inv);
            *(float4*)&out[((size_t)b * Nn + n) * 320 + cc] = o4;
        }
    }
}

// ---------------------------------------------------------------------------
extern "C" void kernel_launch(void* const* d_in, const int* in_sizes, int n_in,
                              void* d_out, int out_size, void* d_ws, size_t ws_size,
                              hipStream_t stream)
{
    const float* s     = (const float*)d_in[0];
    const float* h     = (const float*)d_in[1];
    const float* sh    = (const float*)d_in[2];
    const float* temp  = (const float*)d_in[3];
    const float* temp2 = (const float*)d_in[4];
    const float* Wq_c  = (const float*)d_in[5];
    const float* Wq_s  = (const float*)d_in[6];
    const float* Wk_c  = (const float*)d_in[7];
    const float* Wv_c  = (const float*)d_in[8];
    const float* Wk_s  = (const float*)d_in[9];
    const float* Wv_s  = (const float*)d_in[10];
    float* out = (float*)d_out;
    float* ws = (float*)d_ws;

    ushort* sb    = (ushort*)(ws + OFF_SB);
    ushort* shb   = (ushort*)(ws + OFF_SHB);
    ushort* hb    = (ushort*)(ws + OFF_HB);
    ushort* wqcb  = (ushort*)(ws + OFF_WQC);
    ushort* wcatb = (ushort*)(ws + OFF_WCAT);
    ushort* wvsb  = (ushort*)(ws + OFF_WVS);
    ushort* Pqc   = (ushort*)(ws + OFF_PQC);
    ushort* Pqs   = (ushort*)(ws + OFF_PQS);
    ushort* Pkc   = (ushort*)(ws + OFF_PKC);
    ushort* Pvc   = (ushort*)(ws + OFF_PVC);
    ushort* Pks   = (ushort*)(ws + OFF_PKS);
    ushort* PvsT  = (ushort*)(ws + OFF_PVST);
    float*  part  = ws + OFF_PART;
    ushort* Sca   = (ushort*)(ws + OFF_SCA);

    const dim3 blk(256);

    // 1) f32 -> bf16 conversions
    convert_all<<<dim3((SEG8 / 8 + 255) / 256), blk, 0, stream>>>(
        s, sh, h, Wq_c, Wq_s, Wk_c, Wv_c, Wk_s, Wv_s,
        sb, shb, hb, wqcb, wcatb, wvsb);

    // 2) all projections in ONE dispatch
    proj_all<<<dim3(672), blk, 0, stream>>>(
        shb, wcatb, Pqs, Pkc, Pvc, Pks, sb, wqcb, Pqc, wvsb, hb, PvsT);

    // 3) channel branch stages 1-2 (stage 1 now MFMA)
    chan_qk_mfma<<<dim3(8, 4, 4), blk, 0, stream>>>(Pqc, Pkc, part);
    chan_softmax<<<dim3(16), blk, 0, stream>>>(part, temp, Sca);

    // 4) fused spatial + chan_pv
    spatial_pv<<<dim3(320), dim3(512), 0, stream>>>(
        Pqs, Pks, PvsT, temp2, Sca, Pvc, out);
}